// Round 2
// baseline (3015.844 us; speedup 1.0000x reference)
//
#include <hip/hip_runtime.h>

#define DFEAT 128

// ---------------------------------------------------------------------------
// Kernel 0: detect whether edge_index is int64 (JAX x64 on) or int32.
// int64 little-endian with values < 2^31 => every odd int32 word is 0.
// ---------------------------------------------------------------------------
__global__ void detect_idx_kernel(const int* __restrict__ ei, int* __restrict__ flag) {
    if (threadIdx.x == 0 && blockIdx.x == 0) {
        int orsum = 0;
        for (int i = 0; i < 128; ++i) orsum |= ei[2 * i + 1];
        flag[0] = (orsum == 0) ? 1 : 0;
    }
}

// ---------------------------------------------------------------------------
// Kernel 1: scatter-add aggregation. agg[dst] += x[src], agg lives in d_out.
// One thread per (edge, 4-feature chunk): 32 threads/edge, float4 gather,
// 4 HW fp32 atomics. Grid = E*32 threads.
// ---------------------------------------------------------------------------
__global__ __launch_bounds__(256) void scatter_kernel(
        const float* __restrict__ x, const void* __restrict__ eiv,
        const int* __restrict__ flag, float* __restrict__ agg, int E) {
    unsigned gid = blockIdx.x * 256u + threadIdx.x;
    unsigned e = gid >> 5;
    if (e >= (unsigned)E) return;
    int c = (gid & 31u) * 4;
    int src, dst;
    if (flag[0]) {
        const long long* ei = (const long long*)eiv;
        src = (int)ei[e];
        dst = (int)ei[(size_t)E + e];
    } else {
        const int* ei = (const int*)eiv;
        src = ei[e];
        dst = ei[(size_t)E + e];
    }
    float4 v = *(const float4*)&x[(size_t)src * DFEAT + c];
    float* p = &agg[(size_t)dst * DFEAT + c];
    unsafeAtomicAdd(p + 0, v.x);
    unsafeAtomicAdd(p + 1, v.y);
    unsafeAtomicAdd(p + 2, v.z);
    unsafeAtomicAdd(p + 3, v.w);
}

// ---------------------------------------------------------------------------
// Kernel 2: fused h = (1+eps)*x + agg; out = relu(h@W1+b1)@W2+b2.
// 32 nodes/block, 256 threads. LDS: hs 16KB + Wc 32KB = 48KB (<=64KB static,
// ~3 blocks/CU). Thread tile: 4 nodes x 4 features, k unrolled by 4:
// 64 FMA per 8 ds_read_b128 -> VALU-bound. In-place on d_out (agg read
// before overwrite, block owns its rows).
// ---------------------------------------------------------------------------
__global__ __launch_bounds__(256) void mlp_kernel(
        const float* __restrict__ x,
        const float* __restrict__ W1, const float* __restrict__ b1,
        const float* __restrict__ W2, const float* __restrict__ b2,
        const float* __restrict__ epsp, float* __restrict__ out) {
    __shared__ float hs[32][DFEAT];   // 16 KB: h, then h1 (relu) in place
    __shared__ float Wc[64][DFEAT];   // 32 KB: half-K chunk of W

    const int tid = threadIdx.x;
    const int node0 = blockIdx.x * 32;
    const float epsv = 1.0f + epsp[0];

    // Load h = (1+eps)*x + agg   (agg currently in `out`)
    for (int i = tid; i < 32 * (DFEAT / 4); i += 256) {
        int n = i >> 5;            // 32 float4 per row
        int c = (i & 31) * 4;
        size_t off = (size_t)(node0 + n) * DFEAT + c;
        float4 xv = *(const float4*)&x[off];
        float4 av = *(const float4*)&out[off];
        float4 h;
        h.x = epsv * xv.x + av.x;
        h.y = epsv * xv.y + av.y;
        h.z = epsv * xv.z + av.z;
        h.w = epsv * xv.w + av.w;
        *(float4*)&hs[n][c] = h;
    }

    const int og = (tid & 31) * 4;   // feature base (4 consecutive feats)
    const int ng = (tid >> 5) * 4;   // node base (4 consecutive nodes)

    for (int layer = 0; layer < 2; ++layer) {
        const float* W = layer ? W2 : W1;
        const float* b = layer ? b2 : b1;

        float acc[4][4];
#pragma unroll
        for (int j = 0; j < 4; ++j) {
            float bj = b[og + j];
#pragma unroll
            for (int i = 0; i < 4; ++i) acc[i][j] = bj;
        }

        for (int chunk = 0; chunk < 2; ++chunk) {
            __syncthreads();   // hs/h1 writes visible; Wc safe to overwrite
            for (int i = tid; i < 64 * (DFEAT / 4); i += 256) {
                int r = i >> 5;
                int c = (i & 31) * 4;
                *(float4*)&Wc[r][c] =
                    *(const float4*)&W[(size_t)(chunk * 64 + r) * DFEAT + c];
            }
            __syncthreads();
            const int kb = chunk * 64;
            for (int k = 0; k < 64; k += 4) {
                float4 h4[4], w4[4];
#pragma unroll
                for (int i = 0; i < 4; ++i)
                    h4[i] = *(const float4*)&hs[ng + i][kb + k];   // broadcast
#pragma unroll
                for (int j = 0; j < 4; ++j)
                    w4[j] = *(const float4*)&Wc[k + j][og];        // row b128
#pragma unroll
                for (int i = 0; i < 4; ++i) {
                    acc[i][0] += h4[i].x * w4[0].x + h4[i].y * w4[1].x
                               + h4[i].z * w4[2].x + h4[i].w * w4[3].x;
                    acc[i][1] += h4[i].x * w4[0].y + h4[i].y * w4[1].y
                               + h4[i].z * w4[2].y + h4[i].w * w4[3].y;
                    acc[i][2] += h4[i].x * w4[0].z + h4[i].y * w4[1].z
                               + h4[i].z * w4[2].z + h4[i].w * w4[3].z;
                    acc[i][3] += h4[i].x * w4[0].w + h4[i].y * w4[1].w
                               + h4[i].z * w4[2].w + h4[i].w * w4[3].w;
                }
            }
        }
        __syncthreads();   // all hs reads for this layer done

        if (layer == 0) {
            // h1 = relu(acc) back into hs
#pragma unroll
            for (int i = 0; i < 4; ++i) {
                float4 r;
                r.x = fmaxf(acc[i][0], 0.0f);
                r.y = fmaxf(acc[i][1], 0.0f);
                r.z = fmaxf(acc[i][2], 0.0f);
                r.w = fmaxf(acc[i][3], 0.0f);
                *(float4*)&hs[ng + i][og] = r;
            }
        } else {
#pragma unroll
            for (int i = 0; i < 4; ++i) {
                float4 r;
                r.x = acc[i][0];
                r.y = acc[i][1];
                r.z = acc[i][2];
                r.w = acc[i][3];
                *(float4*)&out[(size_t)(node0 + ng + i) * DFEAT + og] = r;
            }
        }
    }
}

extern "C" void kernel_launch(void* const* d_in, const int* in_sizes, int n_in,
                              void* d_out, int out_size, void* d_ws, size_t ws_size,
                              hipStream_t stream) {
    const float* x   = (const float*)d_in[0];
    const void*  ei  = d_in[1];
    const float* W1  = (const float*)d_in[2];
    const float* b1  = (const float*)d_in[3];
    const float* W2  = (const float*)d_in[4];
    const float* b2  = (const float*)d_in[5];
    const float* eps = (const float*)d_in[6];
    float* out = (float*)d_out;

    const int N = in_sizes[0] / DFEAT;      // 100000
    const int E = in_sizes[1] / 2;          // 1600000

    int* flag = (int*)d_ws;

    // agg accumulates in d_out: zero it first (capture-safe async memset)
    hipMemsetAsync(d_out, 0, (size_t)out_size * sizeof(float), stream);

    detect_idx_kernel<<<1, 64, 0, stream>>>((const int*)ei, flag);

    unsigned total = (unsigned)E * 32u;
    unsigned blocks = (total + 255u) / 256u;
    scatter_kernel<<<blocks, 256, 0, stream>>>(x, ei, flag, out, E);

    mlp_kernel<<<N / 32, 256, 0, stream>>>(x, W1, b1, W2, b2, eps, out);
}

// Round 3
// 648.643 us; speedup vs baseline: 4.6495x; 4.6495x over previous
//
#include <hip/hip_runtime.h>

#define DFEAT 128

// ---------------------------------------------------------------------------
// Kernel 0: detect whether edge_index is int64 (JAX x64 on) or int32.
// int64 little-endian with values < 2^31 => every odd int32 word is 0.
// ---------------------------------------------------------------------------
__global__ void detect_idx_kernel(const int* __restrict__ ei, int* __restrict__ flag) {
    if (threadIdx.x == 0 && blockIdx.x == 0) {
        int orsum = 0;
        for (int i = 0; i < 128; ++i) orsum |= ei[2 * i + 1];
        flag[0] = (orsum == 0) ? 1 : 0;
    }
}

__device__ __forceinline__ int load_idx(const void* eiv, int is64, size_t i) {
    return is64 ? (int)((const long long*)eiv)[i] : ((const int*)eiv)[i];
}

// ---------------------------------------------------------------------------
// CSR build: histogram of dst degrees (deg aliases cursor array).
// ---------------------------------------------------------------------------
__global__ __launch_bounds__(256) void hist_kernel(
        const void* __restrict__ eiv, const int* __restrict__ flag,
        int* __restrict__ deg, int E) {
    int e = blockIdx.x * 256 + threadIdx.x;
    if (e >= E) return;
    int dst = load_idx(eiv, flag[0], (size_t)E + e);
    atomicAdd(&deg[dst], 1);
}

// scan1: per-1024-chunk sums
__global__ __launch_bounds__(256) void scan1_kernel(
        const int* __restrict__ deg, int* __restrict__ sums, int N) {
    __shared__ int s[256];
    int base = blockIdx.x * 1024 + threadIdx.x * 4;
    int tsum = 0;
#pragma unroll
    for (int j = 0; j < 4; ++j) tsum += (base + j < N) ? deg[base + j] : 0;
    s[threadIdx.x] = tsum;
    __syncthreads();
    for (int off = 128; off > 0; off >>= 1) {
        if (threadIdx.x < off) s[threadIdx.x] += s[threadIdx.x + off];
        __syncthreads();
    }
    if (threadIdx.x == 0) sums[blockIdx.x] = s[0];
}

// scan2: exclusive scan of chunk sums (nb <= 1024, trivial sequential)
__global__ void scan2_kernel(int* __restrict__ sums, int nb,
                             int* __restrict__ row_ptr, int N) {
    if (threadIdx.x == 0 && blockIdx.x == 0) {
        int run = 0;
        for (int i = 0; i < nb; ++i) { int t = sums[i]; sums[i] = run; run += t; }
        row_ptr[N] = run;
    }
}

// scan3: block-local exclusive scan + chunk offset -> row_ptr & cursor.
// deg aliases cursor: each cell is read (into regs) before being written,
// and only by its own thread -> safe.
__global__ __launch_bounds__(256) void scan3_kernel(
        const int* __restrict__ deg, const int* __restrict__ sums,
        int* __restrict__ row_ptr, int* __restrict__ cursor, int N) {
    __shared__ int s[256];
    int tid = threadIdx.x;
    int idx = blockIdx.x * 1024 + tid * 4;
    int d[4];
#pragma unroll
    for (int j = 0; j < 4; ++j) d[j] = (idx + j < N) ? deg[idx + j] : 0;
    int tsum = d[0] + d[1] + d[2] + d[3];
    s[tid] = tsum;
    __syncthreads();
    for (int off = 1; off < 256; off <<= 1) {     // Hillis-Steele inclusive
        int t = (tid >= off) ? s[tid - off] : 0;
        __syncthreads();
        s[tid] += t;
        __syncthreads();
    }
    int excl = s[tid] - tsum + sums[blockIdx.x];
#pragma unroll
    for (int j = 0; j < 4; ++j) {
        if (idx + j < N) { row_ptr[idx + j] = excl; cursor[idx + j] = excl; }
        excl += d[j];
    }
}

// fill: col[cursor[dst]++] = src
__global__ __launch_bounds__(256) void fill_kernel(
        const void* __restrict__ eiv, const int* __restrict__ flag,
        int* __restrict__ cursor, int* __restrict__ col, int E) {
    int e = blockIdx.x * 256 + threadIdx.x;
    if (e >= E) return;
    int is64 = flag[0];
    int src = load_idx(eiv, is64, (size_t)e);
    int dst = load_idx(eiv, is64, (size_t)E + e);
    int pos = atomicAdd(&cursor[dst], 1);
    col[pos] = src;
}

// ---------------------------------------------------------------------------
// Gather-aggregate: h[n] = (1+eps)*x[n] + sum_{s in N(n)} x[s], written once.
// 256 threads = 8 groups of 32 lanes; each group owns one node; lane holds
// float4 (feats lane*4..lane*4+3). Neighbor rows are 512B coalesced reads,
// x (51 MB) is L3-resident. 2-way unrolled for load ILP.
// ---------------------------------------------------------------------------
__global__ __launch_bounds__(256) void agg_kernel(
        const float* __restrict__ x, const int* __restrict__ row_ptr,
        const int* __restrict__ col, const float* __restrict__ epsp,
        float* __restrict__ out, int N) {
    int g = threadIdx.x >> 5, lane = threadIdx.x & 31;
    int node = blockIdx.x * 8 + g;
    if (node >= N) return;
    int c = lane * 4;
    float epsv = 1.0f + epsp[0];
    float4 v = *(const float4*)&x[(size_t)node * DFEAT + c];
    float4 acc;
    acc.x = epsv * v.x; acc.y = epsv * v.y;
    acc.z = epsv * v.z; acc.w = epsv * v.w;
    int p = row_ptr[node], end = row_ptr[node + 1];
    for (; p + 1 < end; p += 2) {
        int s0 = col[p], s1 = col[p + 1];
        float4 a = *(const float4*)&x[(size_t)s0 * DFEAT + c];
        float4 b = *(const float4*)&x[(size_t)s1 * DFEAT + c];
        acc.x += a.x + b.x; acc.y += a.y + b.y;
        acc.z += a.z + b.z; acc.w += a.w + b.w;
    }
    if (p < end) {
        int s0 = col[p];
        float4 a = *(const float4*)&x[(size_t)s0 * DFEAT + c];
        acc.x += a.x; acc.y += a.y; acc.z += a.z; acc.w += a.w;
    }
    *(float4*)&out[(size_t)node * DFEAT + c] = acc;
}

// ---------------------------------------------------------------------------
// Fallback (small ws): atomic scatter into d_out (proven R2 path).
// ---------------------------------------------------------------------------
__global__ __launch_bounds__(256) void scatter_kernel(
        const float* __restrict__ x, const void* __restrict__ eiv,
        const int* __restrict__ flag, float* __restrict__ agg, int E) {
    unsigned gid = blockIdx.x * 256u + threadIdx.x;
    unsigned e = gid >> 5;
    if (e >= (unsigned)E) return;
    int c = (gid & 31u) * 4;
    int is64 = flag[0];
    int src = load_idx(eiv, is64, (size_t)e);
    int dst = load_idx(eiv, is64, (size_t)E + e);
    float4 v = *(const float4*)&x[(size_t)src * DFEAT + c];
    float* p = &agg[(size_t)dst * DFEAT + c];
    unsafeAtomicAdd(p + 0, v.x);
    unsafeAtomicAdd(p + 1, v.y);
    unsafeAtomicAdd(p + 2, v.z);
    unsafeAtomicAdd(p + 3, v.w);
}

// ---------------------------------------------------------------------------
// MLP: out = relu(h@W1+b1)@W2+b2, in-place on d_out.
// If xp != nullptr (fallback path): h = (1+eps)*xp + out (agg).
// Else (CSR path): h already in out.
// ---------------------------------------------------------------------------
__global__ __launch_bounds__(256) void mlp_kernel(
        const float* __restrict__ xp,
        const float* __restrict__ W1, const float* __restrict__ b1,
        const float* __restrict__ W2, const float* __restrict__ b2,
        const float* __restrict__ epsp, float* __restrict__ out) {
    __shared__ float hs[32][DFEAT];   // 16 KB
    __shared__ float Wc[64][DFEAT];   // 32 KB

    const int tid = threadIdx.x;
    const int node0 = blockIdx.x * 32;
    const float epsv = 1.0f + epsp[0];

    for (int i = tid; i < 32 * (DFEAT / 4); i += 256) {
        int n = i >> 5;
        int c = (i & 31) * 4;
        size_t off = (size_t)(node0 + n) * DFEAT + c;
        float4 h = *(const float4*)&out[off];
        if (xp) {
            float4 xv = *(const float4*)&xp[off];
            h.x += epsv * xv.x; h.y += epsv * xv.y;
            h.z += epsv * xv.z; h.w += epsv * xv.w;
        }
        *(float4*)&hs[n][c] = h;
    }

    const int og = (tid & 31) * 4;
    const int ng = (tid >> 5) * 4;

    for (int layer = 0; layer < 2; ++layer) {
        const float* W = layer ? W2 : W1;
        const float* b = layer ? b2 : b1;

        float acc[4][4];
#pragma unroll
        for (int j = 0; j < 4; ++j) {
            float bj = b[og + j];
#pragma unroll
            for (int i = 0; i < 4; ++i) acc[i][j] = bj;
        }

        for (int chunk = 0; chunk < 2; ++chunk) {
            __syncthreads();
            for (int i = tid; i < 64 * (DFEAT / 4); i += 256) {
                int r = i >> 5;
                int c = (i & 31) * 4;
                *(float4*)&Wc[r][c] =
                    *(const float4*)&W[(size_t)(chunk * 64 + r) * DFEAT + c];
            }
            __syncthreads();
            const int kb = chunk * 64;
            for (int k = 0; k < 64; k += 4) {
                float4 h4[4], w4[4];
#pragma unroll
                for (int i = 0; i < 4; ++i)
                    h4[i] = *(const float4*)&hs[ng + i][kb + k];
#pragma unroll
                for (int j = 0; j < 4; ++j)
                    w4[j] = *(const float4*)&Wc[k + j][og];
#pragma unroll
                for (int i = 0; i < 4; ++i) {
                    acc[i][0] += h4[i].x * w4[0].x + h4[i].y * w4[1].x
                               + h4[i].z * w4[2].x + h4[i].w * w4[3].x;
                    acc[i][1] += h4[i].x * w4[0].y + h4[i].y * w4[1].y
                               + h4[i].z * w4[2].y + h4[i].w * w4[3].y;
                    acc[i][2] += h4[i].x * w4[0].z + h4[i].y * w4[1].z
                               + h4[i].z * w4[2].z + h4[i].w * w4[3].z;
                    acc[i][3] += h4[i].x * w4[0].w + h4[i].y * w4[1].w
                               + h4[i].z * w4[2].w + h4[i].w * w4[3].w;
                }
            }
        }
        __syncthreads();

        if (layer == 0) {
#pragma unroll
            for (int i = 0; i < 4; ++i) {
                float4 r;
                r.x = fmaxf(acc[i][0], 0.0f);
                r.y = fmaxf(acc[i][1], 0.0f);
                r.z = fmaxf(acc[i][2], 0.0f);
                r.w = fmaxf(acc[i][3], 0.0f);
                *(float4*)&hs[ng + i][og] = r;
            }
        } else {
#pragma unroll
            for (int i = 0; i < 4; ++i) {
                float4 r;
                r.x = acc[i][0]; r.y = acc[i][1];
                r.z = acc[i][2]; r.w = acc[i][3];
                *(float4*)&out[(size_t)(node0 + ng + i) * DFEAT + og] = r;
            }
        }
    }
}

extern "C" void kernel_launch(void* const* d_in, const int* in_sizes, int n_in,
                              void* d_out, int out_size, void* d_ws, size_t ws_size,
                              hipStream_t stream) {
    const float* x   = (const float*)d_in[0];
    const void*  ei  = d_in[1];
    const float* W1  = (const float*)d_in[2];
    const float* b1  = (const float*)d_in[3];
    const float* W2  = (const float*)d_in[4];
    const float* b2  = (const float*)d_in[5];
    const float* eps = (const float*)d_in[6];
    float* out = (float*)d_out;

    const int N = in_sizes[0] / DFEAT;      // 100000
    const int E = in_sizes[1] / 2;          // 1600000
    const int EB = (E + 255) / 256;
    const int nb = (N + 1023) / 1024;       // scan chunks

    // ws layout: [flag (64B pad)] [row_ptr N+1] [cursor N] [col E] [sums 1024]
    int* flag    = (int*)d_ws;
    int* row_ptr = (int*)((char*)d_ws + 64);
    int* cursor  = row_ptr + (N + 1);
    int* col     = cursor + N;
    int* sums    = col + E;
    size_t need = 64 + sizeof(int) * ((size_t)(N + 1) + N + E + 1024);

    detect_idx_kernel<<<1, 64, 0, stream>>>((const int*)ei, flag);

    if (ws_size >= need) {
        // ---- CSR path ----
        hipMemsetAsync(cursor, 0, (size_t)N * sizeof(int), stream);  // deg=0
        hist_kernel<<<EB, 256, 0, stream>>>(ei, flag, cursor, E);
        scan1_kernel<<<nb, 256, 0, stream>>>(cursor, sums, N);
        scan2_kernel<<<1, 64, 0, stream>>>(sums, nb, row_ptr, N);
        scan3_kernel<<<nb, 256, 0, stream>>>(cursor, sums, row_ptr, cursor, N);
        fill_kernel<<<EB, 256, 0, stream>>>(ei, flag, cursor, col, E);
        agg_kernel<<<(N + 7) / 8, 256, 0, stream>>>(x, row_ptr, col, eps, out, N);
        mlp_kernel<<<N / 32, 256, 0, stream>>>(nullptr, W1, b1, W2, b2, eps, out);
    } else {
        // ---- fallback: atomic scatter (R2 path) ----
        hipMemsetAsync(d_out, 0, (size_t)out_size * sizeof(float), stream);
        unsigned total = (unsigned)E * 32u;
        scatter_kernel<<<(total + 255u) / 256u, 256, 0, stream>>>(x, ei, flag, out, E);
        mlp_kernel<<<N / 32, 256, 0, stream>>>(x, W1, b1, W2, b2, eps, out);
    }
}

// Round 4
// 474.316 us; speedup vs baseline: 6.3583x; 1.3675x over previous
//
#include <hip/hip_runtime.h>

#define DFEAT 128

typedef __attribute__((ext_vector_type(8))) short short8v;   // 8 bf16 (4 VGPRs)
typedef __attribute__((ext_vector_type(4))) float f32x4;     // MFMA C/D
typedef __attribute__((ext_vector_type(4))) unsigned short ushort4v;

__device__ __forceinline__ unsigned short f2bf(float f) {
    union { float f; unsigned u; } cv; cv.f = f;
    unsigned u = cv.u + 0x7fffu + ((cv.u >> 16) & 1u);   // RNE
    return (unsigned short)(u >> 16);
}

// ---------------------------------------------------------------------------
// Kernel 0: detect whether edge_index is int64 (JAX x64 on) or int32.
// ---------------------------------------------------------------------------
__global__ void detect_idx_kernel(const int* __restrict__ ei, int* __restrict__ flag) {
    if (threadIdx.x == 0 && blockIdx.x == 0) {
        int orsum = 0;
        for (int i = 0; i < 128; ++i) orsum |= ei[2 * i + 1];
        flag[0] = (orsum == 0) ? 1 : 0;
    }
}

__device__ __forceinline__ int load_idx(const void* eiv, int is64, size_t i) {
    return is64 ? (int)((const long long*)eiv)[i] : ((const int*)eiv)[i];
}

// ---------------------------------------------------------------------------
// W -> bf16 transposed: wbf[n*128+k] = bf16(W[k*128+n]). 128 blocks:
// blocks 0..63 handle W1, 64..127 handle W2. Coalesced read, scattered 2B
// write (128 KB total -- microseconds).
// ---------------------------------------------------------------------------
__global__ __launch_bounds__(256) void convert_w_kernel(
        const float* __restrict__ W1, const float* __restrict__ W2,
        unsigned short* __restrict__ w1bf, unsigned short* __restrict__ w2bf) {
    const float* W = (blockIdx.x < 64) ? W1 : W2;
    unsigned short* o = (blockIdx.x < 64) ? w1bf : w2bf;
    int idx = (blockIdx.x & 63) * 256 + threadIdx.x;   // idx = k*128+n
    int k = idx >> 7, n = idx & 127;
    o[n * 128 + k] = f2bf(W[idx]);
}

// ---------------------------------------------------------------------------
// CSR build
// ---------------------------------------------------------------------------
__global__ __launch_bounds__(256) void hist_kernel(
        const void* __restrict__ eiv, const int* __restrict__ flag,
        int* __restrict__ deg, int E) {
    int e = blockIdx.x * 256 + threadIdx.x;
    if (e >= E) return;
    int dst = load_idx(eiv, flag[0], (size_t)E + e);
    atomicAdd(&deg[dst], 1);
}

__global__ __launch_bounds__(256) void scan1_kernel(
        const int* __restrict__ deg, int* __restrict__ sums, int N) {
    __shared__ int s[256];
    int base = blockIdx.x * 1024 + threadIdx.x * 4;
    int tsum = 0;
#pragma unroll
    for (int j = 0; j < 4; ++j) tsum += (base + j < N) ? deg[base + j] : 0;
    s[threadIdx.x] = tsum;
    __syncthreads();
    for (int off = 128; off > 0; off >>= 1) {
        if (threadIdx.x < off) s[threadIdx.x] += s[threadIdx.x + off];
        __syncthreads();
    }
    if (threadIdx.x == 0) sums[blockIdx.x] = s[0];
}

__global__ void scan2_kernel(int* __restrict__ sums, int nb,
                             int* __restrict__ row_ptr, int N) {
    if (threadIdx.x == 0 && blockIdx.x == 0) {
        int run = 0;
        for (int i = 0; i < nb; ++i) { int t = sums[i]; sums[i] = run; run += t; }
        row_ptr[N] = run;
    }
}

__global__ __launch_bounds__(256) void scan3_kernel(
        const int* __restrict__ deg, const int* __restrict__ sums,
        int* __restrict__ row_ptr, int* __restrict__ cursor, int N) {
    __shared__ int s[256];
    int tid = threadIdx.x;
    int idx = blockIdx.x * 1024 + tid * 4;
    int d[4];
#pragma unroll
    for (int j = 0; j < 4; ++j) d[j] = (idx + j < N) ? deg[idx + j] : 0;
    int tsum = d[0] + d[1] + d[2] + d[3];
    s[tid] = tsum;
    __syncthreads();
    for (int off = 1; off < 256; off <<= 1) {
        int t = (tid >= off) ? s[tid - off] : 0;
        __syncthreads();
        s[tid] += t;
        __syncthreads();
    }
    int excl = s[tid] - tsum + sums[blockIdx.x];
#pragma unroll
    for (int j = 0; j < 4; ++j) {
        if (idx + j < N) { row_ptr[idx + j] = excl; cursor[idx + j] = excl; }
        excl += d[j];
    }
}

__global__ __launch_bounds__(256) void fill_kernel(
        const void* __restrict__ eiv, const int* __restrict__ flag,
        int* __restrict__ cursor, int* __restrict__ col, int E) {
    int e = blockIdx.x * 256 + threadIdx.x;
    if (e >= E) return;
    int is64 = flag[0];
    int src = load_idx(eiv, is64, (size_t)e);
    int dst = load_idx(eiv, is64, (size_t)E + e);
    int pos = atomicAdd(&cursor[dst], 1);
    col[pos] = src;
}

// ---------------------------------------------------------------------------
// Gather-aggregate: h[n] = (1+eps)*x[n] + sum_{s in N(n)} x[s] -> out (fp32)
// ---------------------------------------------------------------------------
__global__ __launch_bounds__(256) void agg_kernel(
        const float* __restrict__ x, const int* __restrict__ row_ptr,
        const int* __restrict__ col, const float* __restrict__ epsp,
        float* __restrict__ out, int N) {
    int g = threadIdx.x >> 5, lane = threadIdx.x & 31;
    int node = blockIdx.x * 8 + g;
    if (node >= N) return;
    int c = lane * 4;
    float epsv = 1.0f + epsp[0];
    float4 v = *(const float4*)&x[(size_t)node * DFEAT + c];
    float4 acc;
    acc.x = epsv * v.x; acc.y = epsv * v.y;
    acc.z = epsv * v.z; acc.w = epsv * v.w;
    int p = row_ptr[node], end = row_ptr[node + 1];
    for (; p + 1 < end; p += 2) {
        int s0 = col[p], s1 = col[p + 1];
        float4 a = *(const float4*)&x[(size_t)s0 * DFEAT + c];
        float4 b = *(const float4*)&x[(size_t)s1 * DFEAT + c];
        acc.x += a.x + b.x; acc.y += a.y + b.y;
        acc.z += a.z + b.z; acc.w += a.w + b.w;
    }
    if (p < end) {
        int s0 = col[p];
        float4 a = *(const float4*)&x[(size_t)s0 * DFEAT + c];
        acc.x += a.x; acc.y += a.y; acc.z += a.z; acc.w += a.w;
    }
    *(float4*)&out[(size_t)node * DFEAT + c] = acc;
}

// ---------------------------------------------------------------------------
// MFMA MLP: out = relu(h@W1+b1)@W2+b2 with bf16 inputs / fp32 accum.
// Block = 64 nodes x 128 feats, 4 waves; wave w owns rows [w*16, w*16+16).
// 16x16x32 bf16 MFMA, verified layouts: A[m=lane&15][k=quad*8+j] contiguous,
// B via W_T[n][k] contiguous, C/D col=lane&15 row=quad*4+reg.
// LDS rows padded to 136 ushorts (272B stride -> uniform banks for b128
// frag reads). 52KB LDS -> 3 blocks/CU. In-place on out (block owns rows).
// ---------------------------------------------------------------------------
__global__ __launch_bounds__(256) void mlp_mfma_kernel(
        const float* __restrict__ hsrc,
        const unsigned short* __restrict__ w1bf,
        const unsigned short* __restrict__ w2bf,
        const float* __restrict__ b1, const float* __restrict__ b2,
        float* __restrict__ out, int N) {
    __shared__ unsigned short hlds[64 * 136];   // h, then h1 (bf16)
    __shared__ unsigned short wlds[128 * 136];  // W1_T, then W2_T (bf16)

    const int tid  = threadIdx.x;
    const int node0 = blockIdx.x * 64;
    const int lane = tid & 63;
    const int w    = tid >> 6;
    const int l15  = lane & 15;
    const int quad = lane >> 4;

    // stage h: fp32 -> bf16, zero-pad tail rows
    for (int i = tid; i < 64 * 32; i += 256) {
        int m = i >> 5, c = (i & 31) * 4;
        int node = node0 + m;
        float4 v = make_float4(0.f, 0.f, 0.f, 0.f);
        if (node < N) v = *(const float4*)&hsrc[(size_t)node * DFEAT + c];
        ushort4v o;
        o.x = f2bf(v.x); o.y = f2bf(v.y); o.z = f2bf(v.z); o.w = f2bf(v.w);
        *(ushort4v*)&hlds[m * 136 + c] = o;
    }
    // stage W1_T
    for (int i = tid; i < 128 * 16; i += 256) {
        int n = i >> 4, k0 = (i & 15) * 8;
        *(short8v*)&wlds[n * 136 + k0] = *(const short8v*)&w1bf[n * 128 + k0];
    }
    __syncthreads();

    const unsigned short* ha = &hlds[(w * 16 + l15) * 136 + quad * 8];

    for (int layer = 0; layer < 2; ++layer) {
        if (layer == 1) {
            __syncthreads();   // everyone done with W1_T
            for (int i = tid; i < 128 * 16; i += 256) {
                int n = i >> 4, k0 = (i & 15) * 8;
                *(short8v*)&wlds[n * 136 + k0] = *(const short8v*)&w2bf[n * 128 + k0];
            }
            __syncthreads();
        }

        f32x4 acc[8];
#pragma unroll
        for (int nt = 0; nt < 8; ++nt) acc[nt] = (f32x4){0.f, 0.f, 0.f, 0.f};

#pragma unroll
        for (int s = 0; s < 4; ++s) {
            short8v a = *(const short8v*)&ha[s * 32];
#pragma unroll
            for (int nt = 0; nt < 8; ++nt) {
                short8v bf = *(const short8v*)&wlds[(nt * 16 + l15) * 136 + quad * 8 + s * 32];
                acc[nt] = __builtin_amdgcn_mfma_f32_16x16x32_bf16(a, bf, acc[nt], 0, 0, 0);
            }
        }

        const float* bias = layer ? b2 : b1;
        if (layer == 0) {
            // h1 = relu(acc + b1) -> back into hlds (own rows only)
#pragma unroll
            for (int nt = 0; nt < 8; ++nt) {
                float bv = bias[nt * 16 + l15];
#pragma unroll
                for (int r = 0; r < 4; ++r) {
                    float v = fmaxf(acc[nt][r] + bv, 0.f);
                    hlds[(w * 16 + quad * 4 + r) * 136 + nt * 16 + l15] = f2bf(v);
                }
            }
        } else {
#pragma unroll
            for (int nt = 0; nt < 8; ++nt) {
                float bv = bias[nt * 16 + l15];
#pragma unroll
                for (int r = 0; r < 4; ++r) {
                    int node = node0 + w * 16 + quad * 4 + r;
                    if (node < N)
                        out[(size_t)node * DFEAT + nt * 16 + l15] = acc[nt][r] + bv;
                }
            }
        }
    }
}

// ---------------------------------------------------------------------------
// Fallback path (small ws): atomic scatter + fp32 vector MLP (R2-proven).
// ---------------------------------------------------------------------------
__global__ __launch_bounds__(256) void scatter_kernel(
        const float* __restrict__ x, const void* __restrict__ eiv,
        const int* __restrict__ flag, float* __restrict__ agg, int E) {
    unsigned gid = blockIdx.x * 256u + threadIdx.x;
    unsigned e = gid >> 5;
    if (e >= (unsigned)E) return;
    int c = (gid & 31u) * 4;
    int is64 = flag[0];
    int src = load_idx(eiv, is64, (size_t)e);
    int dst = load_idx(eiv, is64, (size_t)E + e);
    float4 v = *(const float4*)&x[(size_t)src * DFEAT + c];
    float* p = &agg[(size_t)dst * DFEAT + c];
    unsafeAtomicAdd(p + 0, v.x);
    unsafeAtomicAdd(p + 1, v.y);
    unsafeAtomicAdd(p + 2, v.z);
    unsafeAtomicAdd(p + 3, v.w);
}

__global__ __launch_bounds__(256) void mlp_kernel(
        const float* __restrict__ xp,
        const float* __restrict__ W1, const float* __restrict__ b1,
        const float* __restrict__ W2, const float* __restrict__ b2,
        const float* __restrict__ epsp, float* __restrict__ out) {
    __shared__ float hs[32][DFEAT];
    __shared__ float Wc[64][DFEAT];

    const int tid = threadIdx.x;
    const int node0 = blockIdx.x * 32;
    const float epsv = 1.0f + epsp[0];

    for (int i = tid; i < 32 * (DFEAT / 4); i += 256) {
        int n = i >> 5;
        int c = (i & 31) * 4;
        size_t off = (size_t)(node0 + n) * DFEAT + c;
        float4 h = *(const float4*)&out[off];
        if (xp) {
            float4 xv = *(const float4*)&xp[off];
            h.x += epsv * xv.x; h.y += epsv * xv.y;
            h.z += epsv * xv.z; h.w += epsv * xv.w;
        }
        *(float4*)&hs[n][c] = h;
    }

    const int og = (tid & 31) * 4;
    const int ng = (tid >> 5) * 4;

    for (int layer = 0; layer < 2; ++layer) {
        const float* W = layer ? W2 : W1;
        const float* b = layer ? b2 : b1;

        float acc[4][4];
#pragma unroll
        for (int j = 0; j < 4; ++j) {
            float bj = b[og + j];
#pragma unroll
            for (int i = 0; i < 4; ++i) acc[i][j] = bj;
        }

        for (int chunk = 0; chunk < 2; ++chunk) {
            __syncthreads();
            for (int i = tid; i < 64 * (DFEAT / 4); i += 256) {
                int r = i >> 5;
                int c = (i & 31) * 4;
                *(float4*)&Wc[r][c] =
                    *(const float4*)&W[(size_t)(chunk * 64 + r) * DFEAT + c];
            }
            __syncthreads();
            const int kb = chunk * 64;
            for (int k = 0; k < 64; k += 4) {
                float4 h4[4], w4[4];
#pragma unroll
                for (int i = 0; i < 4; ++i)
                    h4[i] = *(const float4*)&hs[ng + i][kb + k];
#pragma unroll
                for (int j = 0; j < 4; ++j)
                    w4[j] = *(const float4*)&Wc[k + j][og];
#pragma unroll
                for (int i = 0; i < 4; ++i) {
                    acc[i][0] += h4[i].x * w4[0].x + h4[i].y * w4[1].x
                               + h4[i].z * w4[2].x + h4[i].w * w4[3].x;
                    acc[i][1] += h4[i].x * w4[0].y + h4[i].y * w4[1].y
                               + h4[i].z * w4[2].y + h4[i].w * w4[3].y;
                    acc[i][2] += h4[i].x * w4[0].z + h4[i].y * w4[1].z
                               + h4[i].z * w4[2].z + h4[i].w * w4[3].z;
                    acc[i][3] += h4[i].x * w4[0].w + h4[i].y * w4[1].w
                               + h4[i].z * w4[2].w + h4[i].w * w4[3].w;
                }
            }
        }
        __syncthreads();

        if (layer == 0) {
#pragma unroll
            for (int i = 0; i < 4; ++i) {
                float4 r;
                r.x = fmaxf(acc[i][0], 0.0f);
                r.y = fmaxf(acc[i][1], 0.0f);
                r.z = fmaxf(acc[i][2], 0.0f);
                r.w = fmaxf(acc[i][3], 0.0f);
                *(float4*)&hs[ng + i][og] = r;
            }
        } else {
#pragma unroll
            for (int i = 0; i < 4; ++i) {
                float4 r;
                r.x = acc[i][0]; r.y = acc[i][1];
                r.z = acc[i][2]; r.w = acc[i][3];
                *(float4*)&out[(size_t)(node0 + ng + i) * DFEAT + og] = r;
            }
        }
    }
}

extern "C" void kernel_launch(void* const* d_in, const int* in_sizes, int n_in,
                              void* d_out, int out_size, void* d_ws, size_t ws_size,
                              hipStream_t stream) {
    const float* x   = (const float*)d_in[0];
    const void*  ei  = d_in[1];
    const float* W1  = (const float*)d_in[2];
    const float* b1  = (const float*)d_in[3];
    const float* W2  = (const float*)d_in[4];
    const float* b2  = (const float*)d_in[5];
    const float* eps = (const float*)d_in[6];
    float* out = (float*)d_out;

    const int N = in_sizes[0] / DFEAT;      // 100000
    const int E = in_sizes[1] / 2;          // 1600000
    const int EB = (E + 255) / 256;
    const int nb = (N + 1023) / 1024;

    // ws layout: [flag 64B] [w1bf 32KB] [w2bf 32KB] [row_ptr N+1] [cursor N]
    //            [col E] [sums 1024]
    int* flag = (int*)d_ws;
    unsigned short* w1bf = (unsigned short*)((char*)d_ws + 64);
    unsigned short* w2bf = w1bf + 128 * 128;
    int* row_ptr = (int*)((char*)d_ws + 64 + 2 * 128 * 128 * sizeof(unsigned short));
    int* cursor  = row_ptr + (N + 1);
    int* col     = cursor + N;
    int* sums    = col + E;
    size_t need = 64 + 2 * 128 * 128 * sizeof(unsigned short)
                + sizeof(int) * ((size_t)(N + 1) + N + E + 1024);

    detect_idx_kernel<<<1, 64, 0, stream>>>((const int*)ei, flag);

    if (ws_size >= need) {
        // ---- CSR + MFMA path ----
        convert_w_kernel<<<128, 256, 0, stream>>>(W1, W2, w1bf, w2bf);
        hipMemsetAsync(cursor, 0, (size_t)N * sizeof(int), stream);
        hist_kernel<<<EB, 256, 0, stream>>>(ei, flag, cursor, E);
        scan1_kernel<<<nb, 256, 0, stream>>>(cursor, sums, N);
        scan2_kernel<<<1, 64, 0, stream>>>(sums, nb, row_ptr, N);
        scan3_kernel<<<nb, 256, 0, stream>>>(cursor, sums, row_ptr, cursor, N);
        fill_kernel<<<EB, 256, 0, stream>>>(ei, flag, cursor, col, E);
        agg_kernel<<<(N + 7) / 8, 256, 0, stream>>>(x, row_ptr, col, eps, out, N);
        mlp_mfma_kernel<<<(N + 63) / 64, 256, 0, stream>>>(
            out, w1bf, w2bf, b1, b2, out, N);
    } else {
        // ---- fallback: atomic scatter + fp32 MLP ----
        hipMemsetAsync(d_out, 0, (size_t)out_size * sizeof(float), stream);
        unsigned total = (unsigned)E * 32u;
        scatter_kernel<<<(total + 255u) / 256u, 256, 0, stream>>>(x, ei, flag, out, E);
        mlp_kernel<<<N / 32, 256, 0, stream>>>(x, W1, b1, W2, b2, eps, out);
    }
}

// Round 5
// 430.189 us; speedup vs baseline: 7.0105x; 1.1026x over previous
//
#include <hip/hip_runtime.h>

#define DFEAT 128
#define NGRP 8

typedef __attribute__((ext_vector_type(8))) short short8v;   // 8 bf16 (4 VGPRs)
typedef __attribute__((ext_vector_type(4))) float f32x4;     // MFMA C/D
typedef __attribute__((ext_vector_type(4))) unsigned short ushort4v;

__device__ __forceinline__ unsigned short f2bf(float f) {
    union { float f; unsigned u; } cv; cv.f = f;
    unsigned u = cv.u + 0x7fffu + ((cv.u >> 16) & 1u);   // RNE
    return (unsigned short)(u >> 16);
}
__device__ __forceinline__ float bf2f(unsigned short h) {
    union { unsigned u; float f; } cv; cv.u = ((unsigned)h) << 16; return cv.f;
}

// ---------------------------------------------------------------------------
// Kernel 0: detect whether edge_index is int64 (JAX x64 on) or int32.
// ---------------------------------------------------------------------------
__global__ void detect_idx_kernel(const int* __restrict__ ei, int* __restrict__ flag) {
    if (threadIdx.x == 0 && blockIdx.x == 0) {
        int orsum = 0;
        for (int i = 0; i < 128; ++i) orsum |= ei[2 * i + 1];
        flag[0] = (orsum == 0) ? 1 : 0;
    }
}

__device__ __forceinline__ int load_idx(const void* eiv, int is64, size_t i) {
    return is64 ? (int)((const long long*)eiv)[i] : ((const int*)eiv)[i];
}

// ---------------------------------------------------------------------------
// W -> bf16 transposed: wbf[n*128+k] = bf16(W[k*128+n]).
// ---------------------------------------------------------------------------
__global__ __launch_bounds__(256) void convert_w_kernel(
        const float* __restrict__ W1, const float* __restrict__ W2,
        unsigned short* __restrict__ w1bf, unsigned short* __restrict__ w2bf) {
    const float* W = (blockIdx.x < 64) ? W1 : W2;
    unsigned short* o = (blockIdx.x < 64) ? w1bf : w2bf;
    int idx = (blockIdx.x & 63) * 256 + threadIdx.x;   // idx = k*128+n
    int k = idx >> 7, n = idx & 127;
    o[n * 128 + k] = f2bf(W[idx]);
}

// ---------------------------------------------------------------------------
// x -> bf16 (row-major copy), for halved gather traffic in agg.
// ---------------------------------------------------------------------------
__global__ __launch_bounds__(256) void convert_x_kernel(
        const float* __restrict__ x, unsigned short* __restrict__ xb, int total4) {
    int i = blockIdx.x * 256 + threadIdx.x;
    if (i >= total4) return;
    float4 v = *(const float4*)&x[(size_t)i * 4];
    ushort4v o;
    o.x = f2bf(v.x); o.y = f2bf(v.y); o.z = f2bf(v.z); o.w = f2bf(v.w);
    *(ushort4v*)&xb[(size_t)i * 4] = o;
}

// ---------------------------------------------------------------------------
// XCD-partitioned CSR build. Segment index i = grp*N + dst, grp = blockIdx&7.
// hist and fill use the SAME e->blockIdx mapping, so counts match. col is 8
// large regions, each written (mostly) by one XCD -> full-line writebacks.
// ---------------------------------------------------------------------------
__global__ __launch_bounds__(256) void hist_kernel(
        const void* __restrict__ eiv, const int* __restrict__ flag,
        int* __restrict__ deg8, int E, int N) {
    int e = blockIdx.x * 256 + threadIdx.x;
    if (e >= E) return;
    int grp = blockIdx.x & (NGRP - 1);
    int dst = load_idx(eiv, flag[0], (size_t)E + e);
    atomicAdd(&deg8[(size_t)grp * N + dst], 1);
}

// scan1: per-1024-chunk sums over M = NGRP*N entries
__global__ __launch_bounds__(256) void scan1_kernel(
        const int* __restrict__ deg, int* __restrict__ sums, int M) {
    __shared__ int s[256];
    int base = blockIdx.x * 1024 + threadIdx.x * 4;
    int tsum = 0;
#pragma unroll
    for (int j = 0; j < 4; ++j) tsum += (base + j < M) ? deg[base + j] : 0;
    s[threadIdx.x] = tsum;
    __syncthreads();
    for (int off = 128; off > 0; off >>= 1) {
        if (threadIdx.x < off) s[threadIdx.x] += s[threadIdx.x + off];
        __syncthreads();
    }
    if (threadIdx.x == 0) sums[blockIdx.x] = s[0];
}

// scan2: parallel exclusive scan of chunk sums (nb <= 1024), single block.
__global__ __launch_bounds__(256) void scan2_kernel(
        int* __restrict__ sums, int nb, int* __restrict__ total_out) {
    __shared__ int s[256];
    int tid = threadIdx.x;
    int idx = tid * 4;
    int d[4];
#pragma unroll
    for (int j = 0; j < 4; ++j) d[j] = (idx + j < nb) ? sums[idx + j] : 0;
    int tsum = d[0] + d[1] + d[2] + d[3];
    s[tid] = tsum;
    __syncthreads();
    for (int off = 1; off < 256; off <<= 1) {
        int t = (tid >= off) ? s[tid - off] : 0;
        __syncthreads();
        s[tid] += t;
        __syncthreads();
    }
    int excl = s[tid] - tsum;
#pragma unroll
    for (int j = 0; j < 4; ++j) {
        if (idx + j < nb) sums[idx + j] = excl;
        excl += d[j];
    }
    if (tid == 255) total_out[0] = s[255];
}

// scan3: block-local exclusive scan + chunk base -> rp8 & cur8 (aliases deg8)
__global__ __launch_bounds__(256) void scan3_kernel(
        const int* __restrict__ deg, const int* __restrict__ sums,
        int* __restrict__ rp, int* __restrict__ cursor, int M) {
    __shared__ int s[256];
    int tid = threadIdx.x;
    int idx = blockIdx.x * 1024 + tid * 4;
    int d[4];
#pragma unroll
    for (int j = 0; j < 4; ++j) d[j] = (idx + j < M) ? deg[idx + j] : 0;
    int tsum = d[0] + d[1] + d[2] + d[3];
    s[tid] = tsum;
    __syncthreads();
    for (int off = 1; off < 256; off <<= 1) {
        int t = (tid >= off) ? s[tid - off] : 0;
        __syncthreads();
        s[tid] += t;
        __syncthreads();
    }
    int excl = s[tid] - tsum + sums[blockIdx.x];
#pragma unroll
    for (int j = 0; j < 4; ++j) {
        if (idx + j < M) { rp[idx + j] = excl; cursor[idx + j] = excl; }
        excl += d[j];
    }
}

__global__ __launch_bounds__(256) void fill_kernel(
        const void* __restrict__ eiv, const int* __restrict__ flag,
        int* __restrict__ cur8, int* __restrict__ col, int E, int N) {
    int e = blockIdx.x * 256 + threadIdx.x;
    if (e >= E) return;
    int grp = blockIdx.x & (NGRP - 1);
    int is64 = flag[0];
    int src = load_idx(eiv, is64, (size_t)e);
    int dst = load_idx(eiv, is64, (size_t)E + e);
    int pos = atomicAdd(&cur8[(size_t)grp * N + dst], 1);
    col[pos] = src;
}

// ---------------------------------------------------------------------------
// Gather-aggregate over 8 group-segments per node.
// h[n] = (1+eps)*x[n] + sum x[s] -> out (fp32). If xb != nullptr, gather
// bf16 rows (256B/row, half the traffic); else fp32 rows.
// ---------------------------------------------------------------------------
__global__ __launch_bounds__(256) void agg_kernel(
        const float* __restrict__ x, const unsigned short* __restrict__ xb,
        const int* __restrict__ rp8, const int* __restrict__ col,
        const float* __restrict__ epsp, float* __restrict__ out, int N) {
    int g = threadIdx.x >> 5, lane = threadIdx.x & 31;
    int node = blockIdx.x * 8 + g;
    if (node >= N) return;
    int c = lane * 4;
    float epsv = 1.0f + epsp[0];
    float ax, ay, az, aw;

    if (xb) {
        ushort4v sv = *(const ushort4v*)&xb[(size_t)node * DFEAT + c];
        ax = epsv * bf2f(sv.x); ay = epsv * bf2f(sv.y);
        az = epsv * bf2f(sv.z); aw = epsv * bf2f(sv.w);
        for (int g8 = 0; g8 < NGRP; ++g8) {
            int p   = rp8[(size_t)g8 * N + node];
            int end = rp8[(size_t)g8 * N + node + 1];
            for (; p + 1 < end; p += 2) {
                int s0 = col[p], s1 = col[p + 1];
                ushort4v u0 = *(const ushort4v*)&xb[(size_t)s0 * DFEAT + c];
                ushort4v u1 = *(const ushort4v*)&xb[(size_t)s1 * DFEAT + c];
                ax += bf2f(u0.x) + bf2f(u1.x);
                ay += bf2f(u0.y) + bf2f(u1.y);
                az += bf2f(u0.z) + bf2f(u1.z);
                aw += bf2f(u0.w) + bf2f(u1.w);
            }
            if (p < end) {
                int s0 = col[p];
                ushort4v u0 = *(const ushort4v*)&xb[(size_t)s0 * DFEAT + c];
                ax += bf2f(u0.x); ay += bf2f(u0.y);
                az += bf2f(u0.z); aw += bf2f(u0.w);
            }
        }
    } else {
        float4 v = *(const float4*)&x[(size_t)node * DFEAT + c];
        ax = epsv * v.x; ay = epsv * v.y; az = epsv * v.z; aw = epsv * v.w;
        for (int g8 = 0; g8 < NGRP; ++g8) {
            int p   = rp8[(size_t)g8 * N + node];
            int end = rp8[(size_t)g8 * N + node + 1];
            for (; p + 1 < end; p += 2) {
                int s0 = col[p], s1 = col[p + 1];
                float4 a = *(const float4*)&x[(size_t)s0 * DFEAT + c];
                float4 b = *(const float4*)&x[(size_t)s1 * DFEAT + c];
                ax += a.x + b.x; ay += a.y + b.y;
                az += a.z + b.z; aw += a.w + b.w;
            }
            if (p < end) {
                int s0 = col[p];
                float4 a = *(const float4*)&x[(size_t)s0 * DFEAT + c];
                ax += a.x; ay += a.y; az += a.z; aw += a.w;
            }
        }
    }
    *(float4*)&out[(size_t)node * DFEAT + c] = make_float4(ax, ay, az, aw);
}

// ---------------------------------------------------------------------------
// MFMA MLP (R4-proven): out = relu(h@W1+b1)@W2+b2, bf16 in / fp32 accum.
// ---------------------------------------------------------------------------
__global__ __launch_bounds__(256) void mlp_mfma_kernel(
        const float* __restrict__ hsrc,
        const unsigned short* __restrict__ w1bf,
        const unsigned short* __restrict__ w2bf,
        const float* __restrict__ b1, const float* __restrict__ b2,
        float* __restrict__ out, int N) {
    __shared__ unsigned short hlds[64 * 136];
    __shared__ unsigned short wlds[128 * 136];

    const int tid  = threadIdx.x;
    const int node0 = blockIdx.x * 64;
    const int lane = tid & 63;
    const int w    = tid >> 6;
    const int l15  = lane & 15;
    const int quad = lane >> 4;

    for (int i = tid; i < 64 * 32; i += 256) {
        int m = i >> 5, c = (i & 31) * 4;
        int node = node0 + m;
        float4 v = make_float4(0.f, 0.f, 0.f, 0.f);
        if (node < N) v = *(const float4*)&hsrc[(size_t)node * DFEAT + c];
        ushort4v o;
        o.x = f2bf(v.x); o.y = f2bf(v.y); o.z = f2bf(v.z); o.w = f2bf(v.w);
        *(ushort4v*)&hlds[m * 136 + c] = o;
    }
    for (int i = tid; i < 128 * 16; i += 256) {
        int n = i >> 4, k0 = (i & 15) * 8;
        *(short8v*)&wlds[n * 136 + k0] = *(const short8v*)&w1bf[n * 128 + k0];
    }
    __syncthreads();

    const unsigned short* ha = &hlds[(w * 16 + l15) * 136 + quad * 8];

    for (int layer = 0; layer < 2; ++layer) {
        if (layer == 1) {
            __syncthreads();
            for (int i = tid; i < 128 * 16; i += 256) {
                int n = i >> 4, k0 = (i & 15) * 8;
                *(short8v*)&wlds[n * 136 + k0] = *(const short8v*)&w2bf[n * 128 + k0];
            }
            __syncthreads();
        }

        f32x4 acc[8];
#pragma unroll
        for (int nt = 0; nt < 8; ++nt) acc[nt] = (f32x4){0.f, 0.f, 0.f, 0.f};

#pragma unroll
        for (int s = 0; s < 4; ++s) {
            short8v a = *(const short8v*)&ha[s * 32];
#pragma unroll
            for (int nt = 0; nt < 8; ++nt) {
                short8v bf = *(const short8v*)&wlds[(nt * 16 + l15) * 136 + quad * 8 + s * 32];
                acc[nt] = __builtin_amdgcn_mfma_f32_16x16x32_bf16(a, bf, acc[nt], 0, 0, 0);
            }
        }

        const float* bias = layer ? b2 : b1;
        if (layer == 0) {
#pragma unroll
            for (int nt = 0; nt < 8; ++nt) {
                float bv = bias[nt * 16 + l15];
#pragma unroll
                for (int r = 0; r < 4; ++r) {
                    float v = fmaxf(acc[nt][r] + bv, 0.f);
                    hlds[(w * 16 + quad * 4 + r) * 136 + nt * 16 + l15] = f2bf(v);
                }
            }
        } else {
#pragma unroll
            for (int nt = 0; nt < 8; ++nt) {
                float bv = bias[nt * 16 + l15];
#pragma unroll
                for (int r = 0; r < 4; ++r) {
                    int node = node0 + w * 16 + quad * 4 + r;
                    if (node < N)
                        out[(size_t)node * DFEAT + nt * 16 + l15] = acc[nt][r] + bv;
                }
            }
        }
    }
}

// ---------------------------------------------------------------------------
// Last-resort fallback (tiny ws): atomic scatter + fp32 vector MLP.
// ---------------------------------------------------------------------------
__global__ __launch_bounds__(256) void scatter_kernel(
        const float* __restrict__ x, const void* __restrict__ eiv,
        const int* __restrict__ flag, float* __restrict__ agg, int E) {
    unsigned gid = blockIdx.x * 256u + threadIdx.x;
    unsigned e = gid >> 5;
    if (e >= (unsigned)E) return;
    int c = (gid & 31u) * 4;
    int is64 = flag[0];
    int src = load_idx(eiv, is64, (size_t)e);
    int dst = load_idx(eiv, is64, (size_t)E + e);
    float4 v = *(const float4*)&x[(size_t)src * DFEAT + c];
    float* p = &agg[(size_t)dst * DFEAT + c];
    unsafeAtomicAdd(p + 0, v.x);
    unsafeAtomicAdd(p + 1, v.y);
    unsafeAtomicAdd(p + 2, v.z);
    unsafeAtomicAdd(p + 3, v.w);
}

__global__ __launch_bounds__(256) void mlp_kernel(
        const float* __restrict__ xp,
        const float* __restrict__ W1, const float* __restrict__ b1,
        const float* __restrict__ W2, const float* __restrict__ b2,
        const float* __restrict__ epsp, float* __restrict__ out) {
    __shared__ float hs[32][DFEAT];
    __shared__ float Wc[64][DFEAT];

    const int tid = threadIdx.x;
    const int node0 = blockIdx.x * 32;
    const float epsv = 1.0f + epsp[0];

    for (int i = tid; i < 32 * (DFEAT / 4); i += 256) {
        int n = i >> 5;
        int c = (i & 31) * 4;
        size_t off = (size_t)(node0 + n) * DFEAT + c;
        float4 h = *(const float4*)&out[off];
        if (xp) {
            float4 xv = *(const float4*)&xp[off];
            h.x += epsv * xv.x; h.y += epsv * xv.y;
            h.z += epsv * xv.z; h.w += epsv * xv.w;
        }
        *(float4*)&hs[n][c] = h;
    }

    const int og = (tid & 31) * 4;
    const int ng = (tid >> 5) * 4;

    for (int layer = 0; layer < 2; ++layer) {
        const float* W = layer ? W2 : W1;
        const float* b = layer ? b2 : b1;

        float acc[4][4];
#pragma unroll
        for (int j = 0; j < 4; ++j) {
            float bj = b[og + j];
#pragma unroll
            for (int i = 0; i < 4; ++i) acc[i][j] = bj;
        }

        for (int chunk = 0; chunk < 2; ++chunk) {
            __syncthreads();
            for (int i = tid; i < 64 * (DFEAT / 4); i += 256) {
                int r = i >> 5;
                int c = (i & 31) * 4;
                *(float4*)&Wc[r][c] =
                    *(const float4*)&W[(size_t)(chunk * 64 + r) * DFEAT + c];
            }
            __syncthreads();
            const int kb = chunk * 64;
            for (int k = 0; k < 64; k += 4) {
                float4 h4[4], w4[4];
#pragma unroll
                for (int i = 0; i < 4; ++i)
                    h4[i] = *(const float4*)&hs[ng + i][kb + k];
#pragma unroll
                for (int j = 0; j < 4; ++j)
                    w4[j] = *(const float4*)&Wc[k + j][og];
#pragma unroll
                for (int i = 0; i < 4; ++i) {
                    acc[i][0] += h4[i].x * w4[0].x + h4[i].y * w4[1].x
                               + h4[i].z * w4[2].x + h4[i].w * w4[3].x;
                    acc[i][1] += h4[i].x * w4[0].y + h4[i].y * w4[1].y
                               + h4[i].z * w4[2].y + h4[i].w * w4[3].y;
                    acc[i][2] += h4[i].x * w4[0].z + h4[i].y * w4[1].z
                               + h4[i].z * w4[2].z + h4[i].w * w4[3].z;
                    acc[i][3] += h4[i].x * w4[0].w + h4[i].y * w4[1].w
                               + h4[i].z * w4[2].w + h4[i].w * w4[3].w;
                }
            }
        }
        __syncthreads();

        if (layer == 0) {
#pragma unroll
            for (int i = 0; i < 4; ++i) {
                float4 r;
                r.x = fmaxf(acc[i][0], 0.0f);
                r.y = fmaxf(acc[i][1], 0.0f);
                r.z = fmaxf(acc[i][2], 0.0f);
                r.w = fmaxf(acc[i][3], 0.0f);
                *(float4*)&hs[ng + i][og] = r;
            }
        } else {
#pragma unroll
            for (int i = 0; i < 4; ++i) {
                float4 r;
                r.x = acc[i][0]; r.y = acc[i][1];
                r.z = acc[i][2]; r.w = acc[i][3];
                *(float4*)&out[(size_t)(node0 + ng + i) * DFEAT + og] = r;
            }
        }
    }
}

extern "C" void kernel_launch(void* const* d_in, const int* in_sizes, int n_in,
                              void* d_out, int out_size, void* d_ws, size_t ws_size,
                              hipStream_t stream) {
    const float* x   = (const float*)d_in[0];
    const void*  ei  = d_in[1];
    const float* W1  = (const float*)d_in[2];
    const float* b1  = (const float*)d_in[3];
    const float* W2  = (const float*)d_in[4];
    const float* b2  = (const float*)d_in[5];
    const float* eps = (const float*)d_in[6];
    float* out = (float*)d_out;

    const int N = in_sizes[0] / DFEAT;      // 100000
    const int E = in_sizes[1] / 2;          // 1600000
    const int M = NGRP * N;                 // 800000 CSR segments
    const int EB  = (E + 255) / 256;
    const int nb1 = (M + 1023) / 1024;      // 782 (<=1024 for scan2)

    // ws layout (all 64B-aligned for these N/E):
    // [flag 64B][w1bf 32KB][w2bf 32KB][xb N*128*2][rp8 M+16][cur8 M][col E][sums 4KB]
    char* p = (char*)d_ws;
    int* flag = (int*)p;                       p += 64;
    unsigned short* w1bf = (unsigned short*)p; p += 128 * 128 * 2;
    unsigned short* w2bf = (unsigned short*)p; p += 128 * 128 * 2;
    unsigned short* xb = (unsigned short*)p;   size_t xb_bytes = (size_t)N * DFEAT * 2;
    char* p_noxb = p;                          // mid path: skip xb
    char* p_full = p + xb_bytes;

    auto place = [&](char* base, int*& rp8, int*& cur8, int*& col, int*& sums) -> size_t {
        char* q = base;
        rp8  = (int*)q; q += ((size_t)M + 16) * 4;
        cur8 = (int*)q; q += (size_t)M * 4;
        col  = (int*)q; q += (size_t)E * 4;
        sums = (int*)q; q += 4096;
        return (size_t)(q - (char*)d_ws);
    };

    int *rp8, *cur8, *col, *sums;
    size_t need_full = place(p_full, rp8, cur8, col, sums);

    detect_idx_kernel<<<1, 64, 0, stream>>>((const int*)ei, flag);

    bool use_xb = (ws_size >= need_full);
    if (!use_xb) {
        size_t need_mid = place(p_noxb, rp8, cur8, col, sums);
        if (ws_size < need_mid) {
            // ---- last-resort fallback ----
            hipMemsetAsync(d_out, 0, (size_t)out_size * sizeof(float), stream);
            unsigned total = (unsigned)E * 32u;
            scatter_kernel<<<(total + 255u) / 256u, 256, 0, stream>>>(x, ei, flag, out, E);
            mlp_kernel<<<N / 32, 256, 0, stream>>>(x, W1, b1, W2, b2, eps, out);
            return;
        }
    }

    // ---- 8-group CSR + MFMA path ----
    convert_w_kernel<<<128, 256, 0, stream>>>(W1, W2, w1bf, w2bf);
    if (use_xb)
        convert_x_kernel<<<(N * 32 + 255) / 256, 256, 0, stream>>>(x, xb, N * 32);
    hipMemsetAsync(cur8, 0, (size_t)M * sizeof(int), stream);   // deg8 = 0
    hist_kernel<<<EB, 256, 0, stream>>>(ei, flag, cur8, E, N);
    scan1_kernel<<<nb1, 256, 0, stream>>>(cur8, sums, M);
    scan2_kernel<<<1, 256, 0, stream>>>(sums, nb1, rp8 + M);
    scan3_kernel<<<nb1, 256, 0, stream>>>(cur8, sums, rp8, cur8, M);
    fill_kernel<<<EB, 256, 0, stream>>>(ei, flag, cur8, col, E, N);
    agg_kernel<<<(N + 7) / 8, 256, 0, stream>>>(
        x, use_xb ? xb : nullptr, rp8, col, eps, out, N);
    mlp_mfma_kernel<<<(N + 63) / 64, 256, 0, stream>>>(
        out, w1bf, w2bf, b1, b2, out, N);
}

// Round 6
// 390.820 us; speedup vs baseline: 7.7167x; 1.1007x over previous
//
#include <hip/hip_runtime.h>

#define DFEAT 128
#define NGRP 8

typedef __attribute__((ext_vector_type(8))) short short8v;   // 8 bf16 (4 VGPRs)
typedef __attribute__((ext_vector_type(4))) float f32x4;     // MFMA C/D
typedef __attribute__((ext_vector_type(4))) unsigned short ushort4v;

__device__ __forceinline__ unsigned short f2bf(float f) {
    union { float f; unsigned u; } cv; cv.f = f;
    unsigned u = cv.u + 0x7fffu + ((cv.u >> 16) & 1u);   // RNE
    return (unsigned short)(u >> 16);
}
__device__ __forceinline__ float bf2f(unsigned short h) {
    union { unsigned u; float f; } cv; cv.u = ((unsigned)h) << 16; return cv.f;
}

// ---------------------------------------------------------------------------
// Kernel 0: detect whether edge_index is int64 (JAX x64 on) or int32.
// ---------------------------------------------------------------------------
__global__ void detect_idx_kernel(const int* __restrict__ ei, int* __restrict__ flag) {
    if (threadIdx.x == 0 && blockIdx.x == 0) {
        int orsum = 0;
        for (int i = 0; i < 128; ++i) orsum |= ei[2 * i + 1];
        flag[0] = (orsum == 0) ? 1 : 0;
    }
}

__device__ __forceinline__ int load_idx(const void* eiv, int is64, size_t i) {
    return is64 ? (int)((const long long*)eiv)[i] : ((const int*)eiv)[i];
}

// ---------------------------------------------------------------------------
// W -> bf16 transposed: wbf[n*128+k] = bf16(W[k*128+n]).
// ---------------------------------------------------------------------------
__global__ __launch_bounds__(256) void convert_w_kernel(
        const float* __restrict__ W1, const float* __restrict__ W2,
        unsigned short* __restrict__ w1bf, unsigned short* __restrict__ w2bf) {
    const float* W = (blockIdx.x < 64) ? W1 : W2;
    unsigned short* o = (blockIdx.x < 64) ? w1bf : w2bf;
    int idx = (blockIdx.x & 63) * 256 + threadIdx.x;   // idx = k*128+n
    int k = idx >> 7, n = idx & 127;
    o[n * 128 + k] = f2bf(W[idx]);
}

// ---------------------------------------------------------------------------
// x -> bf16 (row-major copy), for halved gather traffic in agg.
// ---------------------------------------------------------------------------
__global__ __launch_bounds__(256) void convert_x_kernel(
        const float* __restrict__ x, unsigned short* __restrict__ xb, int total4) {
    int i = blockIdx.x * 256 + threadIdx.x;
    if (i >= total4) return;
    float4 v = *(const float4*)&x[(size_t)i * 4];
    ushort4v o;
    o.x = f2bf(v.x); o.y = f2bf(v.y); o.z = f2bf(v.z); o.w = f2bf(v.w);
    *(ushort4v*)&xb[(size_t)i * 4] = o;
}

// ---------------------------------------------------------------------------
// XCD-partitioned CSR build. Segment index i = grp*N + dst, grp = blockIdx&7.
// ---------------------------------------------------------------------------
__global__ __launch_bounds__(256) void hist_kernel(
        const void* __restrict__ eiv, const int* __restrict__ flag,
        int* __restrict__ deg8, int E, int N) {
    int e = blockIdx.x * 256 + threadIdx.x;
    if (e >= E) return;
    int grp = blockIdx.x & (NGRP - 1);
    int dst = load_idx(eiv, flag[0], (size_t)E + e);
    atomicAdd(&deg8[(size_t)grp * N + dst], 1);
}

// scan1: per-1024-chunk sums over M = NGRP*N entries
__global__ __launch_bounds__(256) void scan1_kernel(
        const int* __restrict__ deg, int* __restrict__ sums, int M) {
    __shared__ int s[256];
    int base = blockIdx.x * 1024 + threadIdx.x * 4;
    int tsum = 0;
#pragma unroll
    for (int j = 0; j < 4; ++j) tsum += (base + j < M) ? deg[base + j] : 0;
    s[threadIdx.x] = tsum;
    __syncthreads();
    for (int off = 128; off > 0; off >>= 1) {
        if (threadIdx.x < off) s[threadIdx.x] += s[threadIdx.x + off];
        __syncthreads();
    }
    if (threadIdx.x == 0) sums[blockIdx.x] = s[0];
}

// scan2: parallel exclusive scan of chunk sums (nb <= 1024), single block.
__global__ __launch_bounds__(256) void scan2_kernel(
        int* __restrict__ sums, int nb, int* __restrict__ total_out) {
    __shared__ int s[256];
    int tid = threadIdx.x;
    int idx = tid * 4;
    int d[4];
#pragma unroll
    for (int j = 0; j < 4; ++j) d[j] = (idx + j < nb) ? sums[idx + j] : 0;
    int tsum = d[0] + d[1] + d[2] + d[3];
    s[tid] = tsum;
    __syncthreads();
    for (int off = 1; off < 256; off <<= 1) {
        int t = (tid >= off) ? s[tid - off] : 0;
        __syncthreads();
        s[tid] += t;
        __syncthreads();
    }
    int excl = s[tid] - tsum;
#pragma unroll
    for (int j = 0; j < 4; ++j) {
        if (idx + j < nb) sums[idx + j] = excl;
        excl += d[j];
    }
    if (tid == 255) total_out[0] = s[255];
}

// scan3: block-local exclusive scan + chunk base -> rp8 & cur8 (aliases deg8)
__global__ __launch_bounds__(256) void scan3_kernel(
        const int* __restrict__ deg, const int* __restrict__ sums,
        int* __restrict__ rp, int* __restrict__ cursor, int M) {
    __shared__ int s[256];
    int tid = threadIdx.x;
    int idx = blockIdx.x * 1024 + tid * 4;
    int d[4];
#pragma unroll
    for (int j = 0; j < 4; ++j) d[j] = (idx + j < M) ? deg[idx + j] : 0;
    int tsum = d[0] + d[1] + d[2] + d[3];
    s[tid] = tsum;
    __syncthreads();
    for (int off = 1; off < 256; off <<= 1) {
        int t = (tid >= off) ? s[tid - off] : 0;
        __syncthreads();
        s[tid] += t;
        __syncthreads();
    }
    int excl = s[tid] - tsum + sums[blockIdx.x];
#pragma unroll
    for (int j = 0; j < 4; ++j) {
        if (idx + j < M) { rp[idx + j] = excl; cursor[idx + j] = excl; }
        excl += d[j];
    }
}

__global__ __launch_bounds__(256) void fill_kernel(
        const void* __restrict__ eiv, const int* __restrict__ flag,
        int* __restrict__ cur8, int* __restrict__ col, int E, int N) {
    int e = blockIdx.x * 256 + threadIdx.x;
    if (e >= E) return;
    int grp = blockIdx.x & (NGRP - 1);
    int is64 = flag[0];
    int src = load_idx(eiv, is64, (size_t)e);
    int dst = load_idx(eiv, is64, (size_t)E + e);
    int pos = atomicAdd(&cur8[(size_t)grp * N + dst], 1);
    col[pos] = src;
}

// ---------------------------------------------------------------------------
// Gather-aggregate v2: high-MLP drain of all 8 segments concurrently.
// 32-lane group per node. Lane l owns (segment g=l>>2, slot=l&3): predicated
// coalesced loads fetch 4 indices per segment per round; __ballot gives the
// valid mask; iterate set bits 4-at-a-time via __ffs + __shfl broadcast and
// issue 4 independent row gathers back-to-back (latency hiding).
// After fill, cur8[] holds segment ends (no rp8[i+1] reads needed).
// h[n] = (1+eps)*x[n] + sum x[s] -> out (fp32).
// ---------------------------------------------------------------------------
__global__ __launch_bounds__(256) void agg_kernel(
        const float* __restrict__ x, const unsigned short* __restrict__ xb,
        const int* __restrict__ rp8, const int* __restrict__ cur8,
        const int* __restrict__ col, const float* __restrict__ epsp,
        float* __restrict__ out, int N) {
    const int lane = threadIdx.x & 31;
    const int node = blockIdx.x * 8 + (threadIdx.x >> 5);
    if (node >= N) return;
    const int c = lane * 4;
    const int g = lane >> 2, slot = lane & 3;
    const int half = threadIdx.x & 32;          // 0 or 32: wave-half shift
    const float epsv = 1.0f + epsp[0];

    int pg = rp8[(size_t)g * N + node];         // 4-lane broadcast loads
    int eg = cur8[(size_t)g * N + node];

    float ax, ay, az, aw;
    if (xb) {
        ushort4v sv = *(const ushort4v*)&xb[(size_t)node * DFEAT + c];
        ax = epsv * bf2f(sv.x); ay = epsv * bf2f(sv.y);
        az = epsv * bf2f(sv.z); aw = epsv * bf2f(sv.w);
    } else {
        float4 v = *(const float4*)&x[(size_t)node * DFEAT + c];
        ax = epsv * v.x; ay = epsv * v.y; az = epsv * v.z; aw = epsv * v.w;
    }

    for (int r = 0; ; ++r) {
        int off = pg + r * 4 + slot;
        int idx = (off < eg) ? col[off] : -1;
        unsigned long long bal = __ballot(idx >= 0);
        unsigned m = (unsigned)(bal >> half);   // this group's 32-bit mask
        if (m == 0) break;
        while (m) {
            int j0 = __ffs(m) - 1; m &= m - 1;
            int j1 = -1, j2 = -1, j3 = -1;
            if (m) { j1 = __ffs(m) - 1; m &= m - 1; }
            if (m) { j2 = __ffs(m) - 1; m &= m - 1; }
            if (m) { j3 = __ffs(m) - 1; m &= m - 1; }
            int s0 = __shfl(idx, j0, 32);
            int s1 = __shfl(idx, j1 < 0 ? j0 : j1, 32);
            int s2 = __shfl(idx, j2 < 0 ? j0 : j2, 32);
            int s3 = __shfl(idx, j3 < 0 ? j0 : j3, 32);
            if (xb) {
                ushort4v u0 = *(const ushort4v*)&xb[(size_t)s0 * DFEAT + c];
                if (j3 >= 0) {
                    ushort4v u1 = *(const ushort4v*)&xb[(size_t)s1 * DFEAT + c];
                    ushort4v u2 = *(const ushort4v*)&xb[(size_t)s2 * DFEAT + c];
                    ushort4v u3 = *(const ushort4v*)&xb[(size_t)s3 * DFEAT + c];
                    ax += (bf2f(u0.x) + bf2f(u1.x)) + (bf2f(u2.x) + bf2f(u3.x));
                    ay += (bf2f(u0.y) + bf2f(u1.y)) + (bf2f(u2.y) + bf2f(u3.y));
                    az += (bf2f(u0.z) + bf2f(u1.z)) + (bf2f(u2.z) + bf2f(u3.z));
                    aw += (bf2f(u0.w) + bf2f(u1.w)) + (bf2f(u2.w) + bf2f(u3.w));
                } else if (j2 >= 0) {
                    ushort4v u1 = *(const ushort4v*)&xb[(size_t)s1 * DFEAT + c];
                    ushort4v u2 = *(const ushort4v*)&xb[(size_t)s2 * DFEAT + c];
                    ax += bf2f(u0.x) + bf2f(u1.x) + bf2f(u2.x);
                    ay += bf2f(u0.y) + bf2f(u1.y) + bf2f(u2.y);
                    az += bf2f(u0.z) + bf2f(u1.z) + bf2f(u2.z);
                    aw += bf2f(u0.w) + bf2f(u1.w) + bf2f(u2.w);
                } else if (j1 >= 0) {
                    ushort4v u1 = *(const ushort4v*)&xb[(size_t)s1 * DFEAT + c];
                    ax += bf2f(u0.x) + bf2f(u1.x);
                    ay += bf2f(u0.y) + bf2f(u1.y);
                    az += bf2f(u0.z) + bf2f(u1.z);
                    aw += bf2f(u0.w) + bf2f(u1.w);
                } else {
                    ax += bf2f(u0.x); ay += bf2f(u0.y);
                    az += bf2f(u0.z); aw += bf2f(u0.w);
                }
            } else {
                float4 a0 = *(const float4*)&x[(size_t)s0 * DFEAT + c];
                if (j3 >= 0) {
                    float4 a1 = *(const float4*)&x[(size_t)s1 * DFEAT + c];
                    float4 a2 = *(const float4*)&x[(size_t)s2 * DFEAT + c];
                    float4 a3 = *(const float4*)&x[(size_t)s3 * DFEAT + c];
                    ax += (a0.x + a1.x) + (a2.x + a3.x);
                    ay += (a0.y + a1.y) + (a2.y + a3.y);
                    az += (a0.z + a1.z) + (a2.z + a3.z);
                    aw += (a0.w + a1.w) + (a2.w + a3.w);
                } else if (j2 >= 0) {
                    float4 a1 = *(const float4*)&x[(size_t)s1 * DFEAT + c];
                    float4 a2 = *(const float4*)&x[(size_t)s2 * DFEAT + c];
                    ax += a0.x + a1.x + a2.x; ay += a0.y + a1.y + a2.y;
                    az += a0.z + a1.z + a2.z; aw += a0.w + a1.w + a2.w;
                } else if (j1 >= 0) {
                    float4 a1 = *(const float4*)&x[(size_t)s1 * DFEAT + c];
                    ax += a0.x + a1.x; ay += a0.y + a1.y;
                    az += a0.z + a1.z; aw += a0.w + a1.w;
                } else {
                    ax += a0.x; ay += a0.y; az += a0.z; aw += a0.w;
                }
            }
        }
    }
    *(float4*)&out[(size_t)node * DFEAT + c] = make_float4(ax, ay, az, aw);
}

// ---------------------------------------------------------------------------
// MFMA MLP (R4-proven): out = relu(h@W1+b1)@W2+b2, bf16 in / fp32 accum.
// ---------------------------------------------------------------------------
__global__ __launch_bounds__(256) void mlp_mfma_kernel(
        const float* __restrict__ hsrc,
        const unsigned short* __restrict__ w1bf,
        const unsigned short* __restrict__ w2bf,
        const float* __restrict__ b1, const float* __restrict__ b2,
        float* __restrict__ out, int N) {
    __shared__ unsigned short hlds[64 * 136];
    __shared__ unsigned short wlds[128 * 136];

    const int tid  = threadIdx.x;
    const int node0 = blockIdx.x * 64;
    const int lane = tid & 63;
    const int w    = tid >> 6;
    const int l15  = lane & 15;
    const int quad = lane >> 4;

    for (int i = tid; i < 64 * 32; i += 256) {
        int m = i >> 5, c = (i & 31) * 4;
        int node = node0 + m;
        float4 v = make_float4(0.f, 0.f, 0.f, 0.f);
        if (node < N) v = *(const float4*)&hsrc[(size_t)node * DFEAT + c];
        ushort4v o;
        o.x = f2bf(v.x); o.y = f2bf(v.y); o.z = f2bf(v.z); o.w = f2bf(v.w);
        *(ushort4v*)&hlds[m * 136 + c] = o;
    }
    for (int i = tid; i < 128 * 16; i += 256) {
        int n = i >> 4, k0 = (i & 15) * 8;
        *(short8v*)&wlds[n * 136 + k0] = *(const short8v*)&w1bf[n * 128 + k0];
    }
    __syncthreads();

    const unsigned short* ha = &hlds[(w * 16 + l15) * 136 + quad * 8];

    for (int layer = 0; layer < 2; ++layer) {
        if (layer == 1) {
            __syncthreads();
            for (int i = tid; i < 128 * 16; i += 256) {
                int n = i >> 4, k0 = (i & 15) * 8;
                *(short8v*)&wlds[n * 136 + k0] = *(const short8v*)&w2bf[n * 128 + k0];
            }
            __syncthreads();
        }

        f32x4 acc[8];
#pragma unroll
        for (int nt = 0; nt < 8; ++nt) acc[nt] = (f32x4){0.f, 0.f, 0.f, 0.f};

#pragma unroll
        for (int s = 0; s < 4; ++s) {
            short8v a = *(const short8v*)&ha[s * 32];
#pragma unroll
            for (int nt = 0; nt < 8; ++nt) {
                short8v bf = *(const short8v*)&wlds[(nt * 16 + l15) * 136 + quad * 8 + s * 32];
                acc[nt] = __builtin_amdgcn_mfma_f32_16x16x32_bf16(a, bf, acc[nt], 0, 0, 0);
            }
        }

        const float* bias = layer ? b2 : b1;
        if (layer == 0) {
#pragma unroll
            for (int nt = 0; nt < 8; ++nt) {
                float bv = bias[nt * 16 + l15];
#pragma unroll
                for (int r = 0; r < 4; ++r) {
                    float v = fmaxf(acc[nt][r] + bv, 0.f);
                    hlds[(w * 16 + quad * 4 + r) * 136 + nt * 16 + l15] = f2bf(v);
                }
            }
        } else {
#pragma unroll
            for (int nt = 0; nt < 8; ++nt) {
                float bv = bias[nt * 16 + l15];
#pragma unroll
                for (int r = 0; r < 4; ++r) {
                    int node = node0 + w * 16 + quad * 4 + r;
                    if (node < N)
                        out[(size_t)node * DFEAT + nt * 16 + l15] = acc[nt][r] + bv;
                }
            }
        }
    }
}

// ---------------------------------------------------------------------------
// Last-resort fallback (tiny ws): atomic scatter + fp32 vector MLP.
// ---------------------------------------------------------------------------
__global__ __launch_bounds__(256) void scatter_kernel(
        const float* __restrict__ x, const void* __restrict__ eiv,
        const int* __restrict__ flag, float* __restrict__ agg, int E) {
    unsigned gid = blockIdx.x * 256u + threadIdx.x;
    unsigned e = gid >> 5;
    if (e >= (unsigned)E) return;
    int c = (gid & 31u) * 4;
    int is64 = flag[0];
    int src = load_idx(eiv, is64, (size_t)e);
    int dst = load_idx(eiv, is64, (size_t)E + e);
    float4 v = *(const float4*)&x[(size_t)src * DFEAT + c];
    float* p = &agg[(size_t)dst * DFEAT + c];
    unsafeAtomicAdd(p + 0, v.x);
    unsafeAtomicAdd(p + 1, v.y);
    unsafeAtomicAdd(p + 2, v.z);
    unsafeAtomicAdd(p + 3, v.w);
}

__global__ __launch_bounds__(256) void mlp_kernel(
        const float* __restrict__ xp,
        const float* __restrict__ W1, const float* __restrict__ b1,
        const float* __restrict__ W2, const float* __restrict__ b2,
        const float* __restrict__ epsp, float* __restrict__ out) {
    __shared__ float hs[32][DFEAT];
    __shared__ float Wc[64][DFEAT];

    const int tid = threadIdx.x;
    const int node0 = blockIdx.x * 32;
    const float epsv = 1.0f + epsp[0];

    for (int i = tid; i < 32 * (DFEAT / 4); i += 256) {
        int n = i >> 5;
        int c = (i & 31) * 4;
        size_t off = (size_t)(node0 + n) * DFEAT + c;
        float4 h = *(const float4*)&out[off];
        if (xp) {
            float4 xv = *(const float4*)&xp[off];
            h.x += epsv * xv.x; h.y += epsv * xv.y;
            h.z += epsv * xv.z; h.w += epsv * xv.w;
        }
        *(float4*)&hs[n][c] = h;
    }

    const int og = (tid & 31) * 4;
    const int ng = (tid >> 5) * 4;

    for (int layer = 0; layer < 2; ++layer) {
        const float* W = layer ? W2 : W1;
        const float* b = layer ? b2 : b1;

        float acc[4][4];
#pragma unroll
        for (int j = 0; j < 4; ++j) {
            float bj = b[og + j];
#pragma unroll
            for (int i = 0; i < 4; ++i) acc[i][j] = bj;
        }

        for (int chunk = 0; chunk < 2; ++chunk) {
            __syncthreads();
            for (int i = tid; i < 64 * (DFEAT / 4); i += 256) {
                int r = i >> 5;
                int c = (i & 31) * 4;
                *(float4*)&Wc[r][c] =
                    *(const float4*)&W[(size_t)(chunk * 64 + r) * DFEAT + c];
            }
            __syncthreads();
            const int kb = chunk * 64;
            for (int k = 0; k < 64; k += 4) {
                float4 h4[4], w4[4];
#pragma unroll
                for (int i = 0; i < 4; ++i)
                    h4[i] = *(const float4*)&hs[ng + i][kb + k];
#pragma unroll
                for (int j = 0; j < 4; ++j)
                    w4[j] = *(const float4*)&Wc[k + j][og];
#pragma unroll
                for (int i = 0; i < 4; ++i) {
                    acc[i][0] += h4[i].x * w4[0].x + h4[i].y * w4[1].x
                               + h4[i].z * w4[2].x + h4[i].w * w4[3].x;
                    acc[i][1] += h4[i].x * w4[0].y + h4[i].y * w4[1].y
                               + h4[i].z * w4[2].y + h4[i].w * w4[3].y;
                    acc[i][2] += h4[i].x * w4[0].z + h4[i].y * w4[1].z
                               + h4[i].z * w4[2].z + h4[i].w * w4[3].z;
                    acc[i][3] += h4[i].x * w4[0].w + h4[i].y * w4[1].w
                               + h4[i].z * w4[2].w + h4[i].w * w4[3].w;
                }
            }
        }
        __syncthreads();

        if (layer == 0) {
#pragma unroll
            for (int i = 0; i < 4; ++i) {
                float4 r;
                r.x = fmaxf(acc[i][0], 0.0f);
                r.y = fmaxf(acc[i][1], 0.0f);
                r.z = fmaxf(acc[i][2], 0.0f);
                r.w = fmaxf(acc[i][3], 0.0f);
                *(float4*)&hs[ng + i][og] = r;
            }
        } else {
#pragma unroll
            for (int i = 0; i < 4; ++i) {
                float4 r;
                r.x = acc[i][0]; r.y = acc[i][1];
                r.z = acc[i][2]; r.w = acc[i][3];
                *(float4*)&out[(size_t)(node0 + ng + i) * DFEAT + og] = r;
            }
        }
    }
}

extern "C" void kernel_launch(void* const* d_in, const int* in_sizes, int n_in,
                              void* d_out, int out_size, void* d_ws, size_t ws_size,
                              hipStream_t stream) {
    const float* x   = (const float*)d_in[0];
    const void*  ei  = d_in[1];
    const float* W1  = (const float*)d_in[2];
    const float* b1  = (const float*)d_in[3];
    const float* W2  = (const float*)d_in[4];
    const float* b2  = (const float*)d_in[5];
    const float* eps = (const float*)d_in[6];
    float* out = (float*)d_out;

    const int N = in_sizes[0] / DFEAT;      // 100000
    const int E = in_sizes[1] / 2;          // 1600000
    const int M = NGRP * N;                 // 800000 CSR segments
    const int EB  = (E + 255) / 256;
    const int nb1 = (M + 1023) / 1024;      // 782 (<=1024 for scan2)

    // ws layout (all 64B-aligned for these N/E):
    // [flag 64B][w1bf 32KB][w2bf 32KB][xb N*128*2][rp8 M+16][cur8 M][col E][sums 4KB]
    char* p = (char*)d_ws;
    int* flag = (int*)p;                       p += 64;
    unsigned short* w1bf = (unsigned short*)p; p += 128 * 128 * 2;
    unsigned short* w2bf = (unsigned short*)p; p += 128 * 128 * 2;
    unsigned short* xb = (unsigned short*)p;   size_t xb_bytes = (size_t)N * DFEAT * 2;
    char* p_noxb = p;                          // mid path: skip xb
    char* p_full = p + xb_bytes;

    auto place = [&](char* base, int*& rp8, int*& cur8, int*& col, int*& sums) -> size_t {
        char* q = base;
        rp8  = (int*)q; q += ((size_t)M + 16) * 4;
        cur8 = (int*)q; q += (size_t)M * 4;
        col  = (int*)q; q += (size_t)E * 4;
        sums = (int*)q; q += 4096;
        return (size_t)(q - (char*)d_ws);
    };

    int *rp8, *cur8, *col, *sums;
    size_t need_full = place(p_full, rp8, cur8, col, sums);

    detect_idx_kernel<<<1, 64, 0, stream>>>((const int*)ei, flag);

    bool use_xb = (ws_size >= need_full);
    if (!use_xb) {
        size_t need_mid = place(p_noxb, rp8, cur8, col, sums);
        if (ws_size < need_mid) {
            // ---- last-resort fallback ----
            hipMemsetAsync(d_out, 0, (size_t)out_size * sizeof(float), stream);
            unsigned total = (unsigned)E * 32u;
            scatter_kernel<<<(total + 255u) / 256u, 256, 0, stream>>>(x, ei, flag, out, E);
            mlp_kernel<<<N / 32, 256, 0, stream>>>(x, W1, b1, W2, b2, eps, out);
            return;
        }
    }

    // ---- 8-group CSR + MFMA path ----
    convert_w_kernel<<<128, 256, 0, stream>>>(W1, W2, w1bf, w2bf);
    if (use_xb)
        convert_x_kernel<<<(N * 32 + 255) / 256, 256, 0, stream>>>(x, xb, N * 32);
    hipMemsetAsync(cur8, 0, (size_t)M * sizeof(int), stream);   // deg8 = 0
    hist_kernel<<<EB, 256, 0, stream>>>(ei, flag, cur8, E, N);
    scan1_kernel<<<nb1, 256, 0, stream>>>(cur8, sums, M);
    scan2_kernel<<<1, 256, 0, stream>>>(sums, nb1, rp8 + M);
    scan3_kernel<<<nb1, 256, 0, stream>>>(cur8, sums, rp8, cur8, M);
    fill_kernel<<<EB, 256, 0, stream>>>(ei, flag, cur8, col, E, N);
    agg_kernel<<<(N + 7) / 8, 256, 0, stream>>>(
        x, use_xb ? xb : nullptr, rp8, cur8, col, eps, out, N);
    mlp_mfma_kernel<<<(N + 63) / 64, 256, 0, stream>>>(
        out, w1bf, w2bf, b1, b2, out, N);
}

// Round 7
// 345.577 us; speedup vs baseline: 8.7270x; 1.1309x over previous
//
#include <hip/hip_runtime.h>

#define DFEAT 128
#define NGRP 8
#define SSLOT 8          // slab slots per (node, grp) segment
#define OVCAP 32768      // overflow list capacity (expected ~200 used)

typedef __attribute__((ext_vector_type(8))) short short8v;   // 8 bf16
typedef __attribute__((ext_vector_type(4))) float f32x4;     // MFMA C/D
typedef __attribute__((ext_vector_type(4))) unsigned short ushort4v;

__device__ __forceinline__ unsigned short f2bf(float f) {
    union { float f; unsigned u; } cv; cv.f = f;
    unsigned u = cv.u + 0x7fffu + ((cv.u >> 16) & 1u);   // RNE
    return (unsigned short)(u >> 16);
}
__device__ __forceinline__ float bf2f(unsigned short h) {
    union { unsigned u; float f; } cv; cv.u = ((unsigned)h) << 16; return cv.f;
}

__device__ __forceinline__ int load_idx(const void* eiv, int is64, size_t i) {
    return is64 ? (int)((const long long*)eiv)[i] : ((const int*)eiv)[i];
}

// ---------------------------------------------------------------------------
// Fused prep: edge-dtype detect (block 0) + W->bf16 transposed (blocks 0..127)
// + x->bf16 copy (blocks 128..).
// ---------------------------------------------------------------------------
__global__ __launch_bounds__(256) void convert_all_kernel(
        const float* __restrict__ W1, const float* __restrict__ W2,
        unsigned short* __restrict__ w1bf, unsigned short* __restrict__ w2bf,
        const float* __restrict__ x, unsigned short* __restrict__ xb, int total4,
        const int* __restrict__ ei, int* __restrict__ flag) {
    int b = blockIdx.x;
    if (b == 0 && threadIdx.x == 0) {
        int orsum = 0;
#pragma unroll
        for (int i = 0; i < 128; ++i) orsum |= ei[2 * i + 1];
        flag[0] = (orsum == 0) ? 1 : 0;
    }
    if (b < 128) {
        const float* W = (b < 64) ? W1 : W2;
        unsigned short* o = (b < 64) ? w1bf : w2bf;
        int idx = (b & 63) * 256 + threadIdx.x;   // idx = k*128+n
        int k = idx >> 7, n = idx & 127;
        o[n * 128 + k] = f2bf(W[idx]);
    } else {
        int i = (b - 128) * 256 + threadIdx.x;
        if (i < total4) {
            float4 v = *(const float4*)&x[(size_t)i * 4];
            ushort4v o;
            o.x = f2bf(v.x); o.y = f2bf(v.y); o.z = f2bf(v.z); o.w = f2bf(v.w);
            *(ushort4v*)&xb[(size_t)i * 4] = o;
        }
    }
}

// ---------------------------------------------------------------------------
// Direct slab fill (replaces hist+scan+fill). grp = blockIdx&7 ~ XCD id.
// slab layout [node][grp][SSLOT]: each 32B seg / 64B line written by one XCD.
// counts layout [grp][N] (XCD-local atomics). Overflow -> global list.
// ---------------------------------------------------------------------------
__global__ __launch_bounds__(256) void fill_slab_kernel(
        const void* __restrict__ eiv, const int* __restrict__ flag,
        int* __restrict__ counts, int* __restrict__ ovcnt,
        int2* __restrict__ ov, int* __restrict__ slab, int E, int N) {
    int e = blockIdx.x * 256 + threadIdx.x;
    if (e >= E) return;
    int grp = blockIdx.x & (NGRP - 1);
    int is64 = flag[0];
    int src = load_idx(eiv, is64, (size_t)e);
    int dst = load_idx(eiv, is64, (size_t)E + e);
    int pos = atomicAdd(&counts[(size_t)grp * N + dst], 1);
    if (pos < SSLOT) {
        slab[(size_t)dst * (NGRP * SSLOT) + grp * SSLOT + pos] = src;
    } else {
        int o = atomicAdd(ovcnt, 1);
        if (o < OVCAP) ov[o] = make_int2(dst, src);
    }
}

// ---------------------------------------------------------------------------
// Gather-aggregate v3. 32-lane group per node. One int2 slab load per lane
// covers all 64 candidate slots; valid indices compacted to LDS (ballot/popc,
// wave-synchronous); drained with 8 independent row gathers per batch.
// h[n] = (1+eps)*x[n] + sum x[s]; written bf16 to hb (or fp32 to hf).
// ---------------------------------------------------------------------------
__global__ __launch_bounds__(256) void agg_slab_kernel(
        const unsigned short* __restrict__ xb,
        const int* __restrict__ counts,       // [NGRP][N]
        const int* __restrict__ slab,         // [N][NGRP][SSLOT]
        const int* __restrict__ ovcnt, const int2* __restrict__ ov,
        const float* __restrict__ epsp,
        unsigned short* __restrict__ hb,      // bf16 h out (may be null)
        float* __restrict__ hf,               // fp32 h out (used if hb null)
        int N) {
    __shared__ int comp[8][64];
    const int lane = threadIdx.x & 31;
    const int grp  = threadIdx.x >> 5;        // 0..7 (node group in block)
    const int base = threadIdx.x & 32;        // ballot shift for 32-lane group
    const int node = blockIdx.x * 8 + grp;
    if (node >= N) return;
    const int c = lane * 4;
    const float epsv = 1.0f + epsp[0];

    // 2 slab slots per lane: elements lane*2, lane*2+1 -> seg g = lane>>2
    int2 sl = *(const int2*)&slab[(size_t)node * 64 + lane * 2];
    int g = lane >> 2;
    int cnt = min(counts[(size_t)g * N + node], SSLOT);
    int s0 = (lane & 3) * 2;
    bool v0 = s0 < cnt, v1 = (s0 + 1) < cnt;
    unsigned m0 = (unsigned)(__ballot(v0) >> base);
    unsigned m1 = (unsigned)(__ballot(v1) >> base);
    int t0 = __popc(m0);
    int total = t0 + __popc(m1);
    unsigned lt = (lane == 0) ? 0u : (~0u >> (32 - lane));
    if (v0) comp[grp][__popc(m0 & lt)] = sl.x;
    if (v1) comp[grp][t0 + __popc(m1 & lt)] = sl.y;
    // same wave wrote & reads its own slice: no barrier needed (wave-sync LDS)

    ushort4v own = *(const ushort4v*)&xb[(size_t)node * DFEAT + c];
    float ax = epsv * bf2f(own.x), ay = epsv * bf2f(own.y);
    float az = epsv * bf2f(own.z), aw = epsv * bf2f(own.w);

    for (int i = 0; i < total; i += 8) {
        int4 qa = *(const int4*)&comp[grp][i];
        int4 qb = *(const int4*)&comp[grp][i + 4];
        int rem = total - i;
        int sj[8];
        sj[0] = qa.x;
        sj[1] = (rem > 1) ? qa.y : qa.x;
        sj[2] = (rem > 2) ? qa.z : qa.x;
        sj[3] = (rem > 3) ? qa.w : qa.x;
        sj[4] = (rem > 4) ? qb.x : qa.x;
        sj[5] = (rem > 5) ? qb.y : qa.x;
        sj[6] = (rem > 6) ? qb.z : qa.x;
        sj[7] = (rem > 7) ? qb.w : qa.x;
        ushort4v u[8];
#pragma unroll
        for (int j = 0; j < 8; ++j)
            u[j] = *(const ushort4v*)&xb[(size_t)sj[j] * DFEAT + c];
#pragma unroll
        for (int j = 0; j < 8; ++j) {
            if (rem > j) {
                ax += bf2f(u[j].x); ay += bf2f(u[j].y);
                az += bf2f(u[j].z); aw += bf2f(u[j].w);
            }
        }
    }

    // overflow replay (expected ~200 entries total; uniform trip count)
    int ovn = min(ovcnt[0], OVCAP);
    int trips = (ovn + 31) >> 5;
    for (int t = 0; t < trips; ++t) {
        int j = t * 32 + lane;
        int2 e = (j < ovn) ? ov[j] : make_int2(-1, 0);
        unsigned long long b = __ballot(e.x == node);
        unsigned m = (unsigned)(b >> base);
        while (m) {
            int l = __ffs(m) - 1; m &= m - 1;
            int s = __shfl(e.y, base + l, 64);
            ushort4v u = *(const ushort4v*)&xb[(size_t)s * DFEAT + c];
            ax += bf2f(u.x); ay += bf2f(u.y);
            az += bf2f(u.z); aw += bf2f(u.w);
        }
    }

    if (hb) {
        ushort4v hv;
        hv.x = f2bf(ax); hv.y = f2bf(ay); hv.z = f2bf(az); hv.w = f2bf(aw);
        *(ushort4v*)&hb[(size_t)node * DFEAT + c] = hv;
    } else {
        *(float4*)&hf[(size_t)node * DFEAT + c] = make_float4(ax, ay, az, aw);
    }
}

// ---------------------------------------------------------------------------
// MFMA MLP: out = relu(h@W1+b1)@W2+b2, bf16 in / fp32 accum.
// h from hb (bf16, direct LDS stage) or hsrc (fp32, converted).
// ---------------------------------------------------------------------------
__global__ __launch_bounds__(256) void mlp_mfma_kernel(
        const unsigned short* __restrict__ hb,
        const float* __restrict__ hsrc,
        const unsigned short* __restrict__ w1bf,
        const unsigned short* __restrict__ w2bf,
        const float* __restrict__ b1, const float* __restrict__ b2,
        float* __restrict__ out, int N) {
    __shared__ unsigned short hlds[64 * 136];
    __shared__ unsigned short wlds[128 * 136];

    const int tid  = threadIdx.x;
    const int node0 = blockIdx.x * 64;
    const int lane = tid & 63;
    const int w    = tid >> 6;
    const int l15  = lane & 15;
    const int quad = lane >> 4;

    if (hb) {
        for (int i = tid; i < 64 * 16; i += 256) {
            int m = i >> 4, k0 = (i & 15) * 8;
            int node = node0 + m;
            short8v v = {0, 0, 0, 0, 0, 0, 0, 0};
            if (node < N) v = *(const short8v*)&hb[(size_t)node * DFEAT + k0];
            *(short8v*)&hlds[m * 136 + k0] = v;
        }
    } else {
        for (int i = tid; i < 64 * 32; i += 256) {
            int m = i >> 5, c = (i & 31) * 4;
            int node = node0 + m;
            float4 v = make_float4(0.f, 0.f, 0.f, 0.f);
            if (node < N) v = *(const float4*)&hsrc[(size_t)node * DFEAT + c];
            ushort4v o;
            o.x = f2bf(v.x); o.y = f2bf(v.y); o.z = f2bf(v.z); o.w = f2bf(v.w);
            *(ushort4v*)&hlds[m * 136 + c] = o;
        }
    }
    for (int i = tid; i < 128 * 16; i += 256) {
        int n = i >> 4, k0 = (i & 15) * 8;
        *(short8v*)&wlds[n * 136 + k0] = *(const short8v*)&w1bf[n * 128 + k0];
    }
    __syncthreads();

    const unsigned short* ha = &hlds[(w * 16 + l15) * 136 + quad * 8];

    for (int layer = 0; layer < 2; ++layer) {
        if (layer == 1) {
            __syncthreads();
            for (int i = tid; i < 128 * 16; i += 256) {
                int n = i >> 4, k0 = (i & 15) * 8;
                *(short8v*)&wlds[n * 136 + k0] = *(const short8v*)&w2bf[n * 128 + k0];
            }
            __syncthreads();
        }

        f32x4 acc[8];
#pragma unroll
        for (int nt = 0; nt < 8; ++nt) acc[nt] = (f32x4){0.f, 0.f, 0.f, 0.f};

#pragma unroll
        for (int s = 0; s < 4; ++s) {
            short8v a = *(const short8v*)&ha[s * 32];
#pragma unroll
            for (int nt = 0; nt < 8; ++nt) {
                short8v bf = *(const short8v*)&wlds[(nt * 16 + l15) * 136 + quad * 8 + s * 32];
                acc[nt] = __builtin_amdgcn_mfma_f32_16x16x32_bf16(a, bf, acc[nt], 0, 0, 0);
            }
        }

        const float* bias = layer ? b2 : b1;
        if (layer == 0) {
#pragma unroll
            for (int nt = 0; nt < 8; ++nt) {
                float bv = bias[nt * 16 + l15];
#pragma unroll
                for (int r = 0; r < 4; ++r) {
                    float v = fmaxf(acc[nt][r] + bv, 0.f);
                    hlds[(w * 16 + quad * 4 + r) * 136 + nt * 16 + l15] = f2bf(v);
                }
            }
        } else {
#pragma unroll
            for (int nt = 0; nt < 8; ++nt) {
                float bv = bias[nt * 16 + l15];
#pragma unroll
                for (int r = 0; r < 4; ++r) {
                    int node = node0 + w * 16 + quad * 4 + r;
                    if (node < N)
                        out[(size_t)node * DFEAT + nt * 16 + l15] = acc[nt][r] + bv;
                }
            }
        }
    }
}

// ===========================================================================
// T2 fallback: R6-proven 8-group CSR path (hist + scan + fill + ballot agg)
// ===========================================================================
__global__ __launch_bounds__(256) void hist_kernel(
        const void* __restrict__ eiv, const int* __restrict__ flag,
        int* __restrict__ deg8, int E, int N) {
    int e = blockIdx.x * 256 + threadIdx.x;
    if (e >= E) return;
    int grp = blockIdx.x & (NGRP - 1);
    int dst = load_idx(eiv, flag[0], (size_t)E + e);
    atomicAdd(&deg8[(size_t)grp * N + dst], 1);
}

__global__ __launch_bounds__(256) void scan1_kernel(
        const int* __restrict__ deg, int* __restrict__ sums, int M) {
    __shared__ int s[256];
    int base = blockIdx.x * 1024 + threadIdx.x * 4;
    int tsum = 0;
#pragma unroll
    for (int j = 0; j < 4; ++j) tsum += (base + j < M) ? deg[base + j] : 0;
    s[threadIdx.x] = tsum;
    __syncthreads();
    for (int off = 128; off > 0; off >>= 1) {
        if (threadIdx.x < off) s[threadIdx.x] += s[threadIdx.x + off];
        __syncthreads();
    }
    if (threadIdx.x == 0) sums[blockIdx.x] = s[0];
}

__global__ __launch_bounds__(256) void scan2_kernel(
        int* __restrict__ sums, int nb, int* __restrict__ total_out) {
    __shared__ int s[256];
    int tid = threadIdx.x;
    int idx = tid * 4;
    int d[4];
#pragma unroll
    for (int j = 0; j < 4; ++j) d[j] = (idx + j < nb) ? sums[idx + j] : 0;
    int tsum = d[0] + d[1] + d[2] + d[3];
    s[tid] = tsum;
    __syncthreads();
    for (int off = 1; off < 256; off <<= 1) {
        int t = (tid >= off) ? s[tid - off] : 0;
        __syncthreads();
        s[tid] += t;
        __syncthreads();
    }
    int excl = s[tid] - tsum;
#pragma unroll
    for (int j = 0; j < 4; ++j) {
        if (idx + j < nb) sums[idx + j] = excl;
        excl += d[j];
    }
    if (tid == 255) total_out[0] = s[255];
}

__global__ __launch_bounds__(256) void scan3_kernel(
        const int* __restrict__ deg, const int* __restrict__ sums,
        int* __restrict__ rp, int* __restrict__ cursor, int M) {
    __shared__ int s[256];
    int tid = threadIdx.x;
    int idx = blockIdx.x * 1024 + tid * 4;
    int d[4];
#pragma unroll
    for (int j = 0; j < 4; ++j) d[j] = (idx + j < M) ? deg[idx + j] : 0;
    int tsum = d[0] + d[1] + d[2] + d[3];
    s[tid] = tsum;
    __syncthreads();
    for (int off = 1; off < 256; off <<= 1) {
        int t = (tid >= off) ? s[tid - off] : 0;
        __syncthreads();
        s[tid] += t;
        __syncthreads();
    }
    int excl = s[tid] - tsum + sums[blockIdx.x];
#pragma unroll
    for (int j = 0; j < 4; ++j) {
        if (idx + j < M) { rp[idx + j] = excl; cursor[idx + j] = excl; }
        excl += d[j];
    }
}

__global__ __launch_bounds__(256) void fill_kernel(
        const void* __restrict__ eiv, const int* __restrict__ flag,
        int* __restrict__ cur8, int* __restrict__ col, int E, int N) {
    int e = blockIdx.x * 256 + threadIdx.x;
    if (e >= E) return;
    int grp = blockIdx.x & (NGRP - 1);
    int is64 = flag[0];
    int src = load_idx(eiv, is64, (size_t)e);
    int dst = load_idx(eiv, is64, (size_t)E + e);
    int pos = atomicAdd(&cur8[(size_t)grp * N + dst], 1);
    col[pos] = src;
}

__global__ __launch_bounds__(256) void agg_kernel(
        const float* __restrict__ x, const unsigned short* __restrict__ xb,
        const int* __restrict__ rp8, const int* __restrict__ cur8,
        const int* __restrict__ col, const float* __restrict__ epsp,
        float* __restrict__ out, int N) {
    const int lane = threadIdx.x & 31;
    const int node = blockIdx.x * 8 + (threadIdx.x >> 5);
    if (node >= N) return;
    const int c = lane * 4;
    const int g = lane >> 2, slot = lane & 3;
    const int half = threadIdx.x & 32;
    const float epsv = 1.0f + epsp[0];

    int pg = rp8[(size_t)g * N + node];
    int eg = cur8[(size_t)g * N + node];

    ushort4v sv = *(const ushort4v*)&xb[(size_t)node * DFEAT + c];
    float ax = epsv * bf2f(sv.x), ay = epsv * bf2f(sv.y);
    float az = epsv * bf2f(sv.z), aw = epsv * bf2f(sv.w);

    for (int r = 0; ; ++r) {
        int off = pg + r * 4 + slot;
        int idx = (off < eg) ? col[off] : -1;
        unsigned long long bal = __ballot(idx >= 0);
        unsigned m = (unsigned)(bal >> half);
        if (m == 0) break;
        while (m) {
            int j0 = __ffs(m) - 1; m &= m - 1;
            int j1 = -1, j2 = -1, j3 = -1;
            if (m) { j1 = __ffs(m) - 1; m &= m - 1; }
            if (m) { j2 = __ffs(m) - 1; m &= m - 1; }
            if (m) { j3 = __ffs(m) - 1; m &= m - 1; }
            int s0 = __shfl(idx, j0, 32);
            int s1 = __shfl(idx, j1 < 0 ? j0 : j1, 32);
            int s2 = __shfl(idx, j2 < 0 ? j0 : j2, 32);
            int s3 = __shfl(idx, j3 < 0 ? j0 : j3, 32);
            ushort4v u0 = *(const ushort4v*)&xb[(size_t)s0 * DFEAT + c];
            if (j3 >= 0) {
                ushort4v u1 = *(const ushort4v*)&xb[(size_t)s1 * DFEAT + c];
                ushort4v u2 = *(const ushort4v*)&xb[(size_t)s2 * DFEAT + c];
                ushort4v u3 = *(const ushort4v*)&xb[(size_t)s3 * DFEAT + c];
                ax += (bf2f(u0.x) + bf2f(u1.x)) + (bf2f(u2.x) + bf2f(u3.x));
                ay += (bf2f(u0.y) + bf2f(u1.y)) + (bf2f(u2.y) + bf2f(u3.y));
                az += (bf2f(u0.z) + bf2f(u1.z)) + (bf2f(u2.z) + bf2f(u3.z));
                aw += (bf2f(u0.w) + bf2f(u1.w)) + (bf2f(u2.w) + bf2f(u3.w));
            } else if (j2 >= 0) {
                ushort4v u1 = *(const ushort4v*)&xb[(size_t)s1 * DFEAT + c];
                ushort4v u2 = *(const ushort4v*)&xb[(size_t)s2 * DFEAT + c];
                ax += bf2f(u0.x) + bf2f(u1.x) + bf2f(u2.x);
                ay += bf2f(u0.y) + bf2f(u1.y) + bf2f(u2.y);
                az += bf2f(u0.z) + bf2f(u1.z) + bf2f(u2.z);
                aw += bf2f(u0.w) + bf2f(u1.w) + bf2f(u2.w);
            } else if (j1 >= 0) {
                ushort4v u1 = *(const ushort4v*)&xb[(size_t)s1 * DFEAT + c];
                ax += bf2f(u0.x) + bf2f(u1.x);
                ay += bf2f(u0.y) + bf2f(u1.y);
                az += bf2f(u0.z) + bf2f(u1.z);
                aw += bf2f(u0.w) + bf2f(u1.w);
            } else {
                ax += bf2f(u0.x); ay += bf2f(u0.y);
                az += bf2f(u0.z); aw += bf2f(u0.w);
            }
        }
    }
    *(float4*)&out[(size_t)node * DFEAT + c] = make_float4(ax, ay, az, aw);
}

// ===========================================================================
// T3 fallback: atomic scatter + fp32 vector MLP
// ===========================================================================
__global__ void detect_idx_kernel(const int* __restrict__ ei, int* __restrict__ flag) {
    if (threadIdx.x == 0 && blockIdx.x == 0) {
        int orsum = 0;
#pragma unroll
        for (int i = 0; i < 128; ++i) orsum |= ei[2 * i + 1];
        flag[0] = (orsum == 0) ? 1 : 0;
    }
}

__global__ __launch_bounds__(256) void scatter_kernel(
        const float* __restrict__ x, const void* __restrict__ eiv,
        const int* __restrict__ flag, float* __restrict__ agg, int E) {
    unsigned gid = blockIdx.x * 256u + threadIdx.x;
    unsigned e = gid >> 5;
    if (e >= (unsigned)E) return;
    int c = (gid & 31u) * 4;
    int is64 = flag[0];
    int src = load_idx(eiv, is64, (size_t)e);
    int dst = load_idx(eiv, is64, (size_t)E + e);
    float4 v = *(const float4*)&x[(size_t)src * DFEAT + c];
    float* p = &agg[(size_t)dst * DFEAT + c];
    unsafeAtomicAdd(p + 0, v.x);
    unsafeAtomicAdd(p + 1, v.y);
    unsafeAtomicAdd(p + 2, v.z);
    unsafeAtomicAdd(p + 3, v.w);
}

__global__ __launch_bounds__(256) void mlp_kernel(
        const float* __restrict__ xp,
        const float* __restrict__ W1, const float* __restrict__ b1,
        const float* __restrict__ W2, const float* __restrict__ b2,
        const float* __restrict__ epsp, float* __restrict__ out) {
    __shared__ float hs[32][DFEAT];
    __shared__ float Wc[64][DFEAT];

    const int tid = threadIdx.x;
    const int node0 = blockIdx.x * 32;
    const float epsv = 1.0f + epsp[0];

    for (int i = tid; i < 32 * (DFEAT / 4); i += 256) {
        int n = i >> 5;
        int c = (i & 31) * 4;
        size_t off = (size_t)(node0 + n) * DFEAT + c;
        float4 h = *(const float4*)&out[off];
        float4 xv = *(const float4*)&xp[off];
        h.x += epsv * xv.x; h.y += epsv * xv.y;
        h.z += epsv * xv.z; h.w += epsv * xv.w;
        *(float4*)&hs[n][c] = h;
    }

    const int og = (tid & 31) * 4;
    const int ng = (tid >> 5) * 4;

    for (int layer = 0; layer < 2; ++layer) {
        const float* W = layer ? W2 : W1;
        const float* b = layer ? b2 : b1;

        float acc[4][4];
#pragma unroll
        for (int j = 0; j < 4; ++j) {
            float bj = b[og + j];
#pragma unroll
            for (int i = 0; i < 4; ++i) acc[i][j] = bj;
        }

        for (int chunk = 0; chunk < 2; ++chunk) {
            __syncthreads();
            for (int i = tid; i < 64 * (DFEAT / 4); i += 256) {
                int r = i >> 5;
                int c = (i & 31) * 4;
                *(float4*)&Wc[r][c] =
                    *(const float4*)&W[(size_t)(chunk * 64 + r) * DFEAT + c];
            }
            __syncthreads();
            const int kb = chunk * 64;
            for (int k = 0; k < 64; k += 4) {
                float4 h4[4], w4[4];
#pragma unroll
                for (int i = 0; i < 4; ++i)
                    h4[i] = *(const float4*)&hs[ng + i][kb + k];
#pragma unroll
                for (int j = 0; j < 4; ++j)
                    w4[j] = *(const float4*)&Wc[k + j][og];
#pragma unroll
                for (int i = 0; i < 4; ++i) {
                    acc[i][0] += h4[i].x * w4[0].x + h4[i].y * w4[1].x
                               + h4[i].z * w4[2].x + h4[i].w * w4[3].x;
                    acc[i][1] += h4[i].x * w4[0].y + h4[i].y * w4[1].y
                               + h4[i].z * w4[2].y + h4[i].w * w4[3].y;
                    acc[i][2] += h4[i].x * w4[0].z + h4[i].y * w4[1].z
                               + h4[i].z * w4[2].z + h4[i].w * w4[3].z;
                    acc[i][3] += h4[i].x * w4[0].w + h4[i].y * w4[1].w
                               + h4[i].z * w4[2].w + h4[i].w * w4[3].w;
                }
            }
        }
        __syncthreads();

        if (layer == 0) {
#pragma unroll
            for (int i = 0; i < 4; ++i) {
                float4 r;
                r.x = fmaxf(acc[i][0], 0.0f);
                r.y = fmaxf(acc[i][1], 0.0f);
                r.z = fmaxf(acc[i][2], 0.0f);
                r.w = fmaxf(acc[i][3], 0.0f);
                *(float4*)&hs[ng + i][og] = r;
            }
        } else {
#pragma unroll
            for (int i = 0; i < 4; ++i) {
                float4 r;
                r.x = acc[i][0]; r.y = acc[i][1];
                r.z = acc[i][2]; r.w = acc[i][3];
                *(float4*)&out[(size_t)(node0 + ng + i) * DFEAT + og] = r;
            }
        }
    }
}

extern "C" void kernel_launch(void* const* d_in, const int* in_sizes, int n_in,
                              void* d_out, int out_size, void* d_ws, size_t ws_size,
                              hipStream_t stream) {
    const float* x   = (const float*)d_in[0];
    const void*  ei  = d_in[1];
    const float* W1  = (const float*)d_in[2];
    const float* b1  = (const float*)d_in[3];
    const float* W2  = (const float*)d_in[4];
    const float* b2  = (const float*)d_in[5];
    const float* eps = (const float*)d_in[6];
    float* out = (float*)d_out;

    const int N = in_sizes[0] / DFEAT;      // 100000
    const int E = in_sizes[1] / 2;          // 1600000
    const int M = NGRP * N;                 // 800000 segments
    const int EB = (E + 255) / 256;
    const int total4 = N * (DFEAT / 4);     // 3.2M float4s in x

    // ---- T1 layout: [flag][wbf][xb][counts][ovcnt][ov][slab][hb?] ----
    char* p = (char*)d_ws;
    int* flag = (int*)p;                        p += 64;
    unsigned short* w1bf = (unsigned short*)p;  p += 128 * 128 * 2;
    unsigned short* w2bf = (unsigned short*)p;  p += 128 * 128 * 2;
    unsigned short* xb = (unsigned short*)p;    p += (size_t)N * DFEAT * 2;
    int* counts = (int*)p;                      p += (size_t)M * 4;
    int* ovcnt = (int*)p;                       p += 64;
    int2* ov = (int2*)p;                        p += (size_t)OVCAP * 8;
    int* slab = (int*)p;                        p += (size_t)N * NGRP * SSLOT * 4;
    size_t need_slim = (size_t)(p - (char*)d_ws);
    unsigned short* hb = (unsigned short*)p;    p += (size_t)N * DFEAT * 2;
    size_t need_full = (size_t)(p - (char*)d_ws);

    if (ws_size >= need_slim) {
        bool full = (ws_size >= need_full);
        convert_all_kernel<<<128 + (total4 + 255) / 256, 256, 0, stream>>>(
            W1, W2, w1bf, w2bf, x, xb, total4, (const int*)ei, flag);
        hipMemsetAsync(counts, 0, (size_t)M * 4 + 64, stream);  // counts + ovcnt
        fill_slab_kernel<<<EB, 256, 0, stream>>>(
            ei, flag, counts, ovcnt, ov, slab, E, N);
        agg_slab_kernel<<<(N + 7) / 8, 256, 0, stream>>>(
            xb, counts, slab, ovcnt, ov, eps,
            full ? hb : nullptr, out, N);
        mlp_mfma_kernel<<<(N + 63) / 64, 256, 0, stream>>>(
            full ? hb : nullptr, out, w1bf, w2bf, b1, b2, out, N);
        return;
    }

    // ---- T2: R6 CSR path ----
    {
        char* q = (char*)d_ws;
        int* flag2 = (int*)q;                        q += 64;
        unsigned short* w1b = (unsigned short*)q;    q += 128 * 128 * 2;
        unsigned short* w2b = (unsigned short*)q;    q += 128 * 128 * 2;
        unsigned short* xb2 = (unsigned short*)q;    q += (size_t)N * DFEAT * 2;
        int* rp8  = (int*)q;                         q += ((size_t)M + 16) * 4;
        int* cur8 = (int*)q;                         q += (size_t)M * 4;
        int* col  = (int*)q;                         q += (size_t)E * 4;
        int* sums = (int*)q;                         q += 4096;
        size_t need_t2 = (size_t)(q - (char*)d_ws);
        const int nb1 = (M + 1023) / 1024;

        if (ws_size >= need_t2) {
            convert_all_kernel<<<128 + (total4 + 255) / 256, 256, 0, stream>>>(
                W1, W2, w1b, w2b, x, xb2, total4, (const int*)ei, flag2);
            hipMemsetAsync(cur8, 0, (size_t)M * 4, stream);
            hist_kernel<<<EB, 256, 0, stream>>>(ei, flag2, cur8, E, N);
            scan1_kernel<<<nb1, 256, 0, stream>>>(cur8, sums, M);
            scan2_kernel<<<1, 256, 0, stream>>>(sums, nb1, rp8 + M);
            scan3_kernel<<<nb1, 256, 0, stream>>>(cur8, sums, rp8, cur8, M);
            fill_kernel<<<EB, 256, 0, stream>>>(ei, flag2, cur8, col, E, N);
            agg_kernel<<<(N + 7) / 8, 256, 0, stream>>>(
                x, xb2, rp8, cur8, col, eps, out, N);
            mlp_mfma_kernel<<<(N + 63) / 64, 256, 0, stream>>>(
                nullptr, out, w1b, w2b, b1, b2, out, N);
            return;
        }
    }

    // ---- T3: atomic fallback ----
    int* flag3 = (int*)d_ws;
    detect_idx_kernel<<<1, 64, 0, stream>>>((const int*)ei, flag3);
    hipMemsetAsync(d_out, 0, (size_t)out_size * sizeof(float), stream);
    unsigned total = (unsigned)E * 32u;
    scatter_kernel<<<(total + 255u) / 256u, 256, 0, stream>>>(x, ei, flag3, out, E);
    mlp_kernel<<<N / 32, 256, 0, stream>>>(x, W1, b1, W2, b2, eps, out);
}

// Round 8
// 303.473 us; speedup vs baseline: 9.9378x; 1.1387x over previous
//
#include <hip/hip_runtime.h>

#define DFEAT 128
#define NGRP 8
#define SSLOT 8          // slab slots per (grp, node) segment
#define OVCAP 32768      // overflow list capacity (expected ~1K used)
#define FILL_BLOCKS 2048 // co-resident fill grid (8 blocks/CU x 256 CU)
#define EPT 8            // max edges per fill thread

typedef __attribute__((ext_vector_type(8))) short short8v;   // 8 bf16
typedef __attribute__((ext_vector_type(4))) float f32x4;     // MFMA C/D
typedef __attribute__((ext_vector_type(4))) unsigned short ushort4v;

__device__ __forceinline__ unsigned short f2bf(float f) {
    union { float f; unsigned u; } cv; cv.f = f;
    unsigned u = cv.u + 0x7fffu + ((cv.u >> 16) & 1u);   // RNE
    return (unsigned short)(u >> 16);
}
__device__ __forceinline__ float bf2f(unsigned short h) {
    union { unsigned u; float f; } cv; cv.u = ((unsigned)h) << 16; return cv.f;
}
__device__ __forceinline__ int load_idx(const void* eiv, int is64, size_t i) {
    return is64 ? (int)((const long long*)eiv)[i] : ((const int*)eiv)[i];
}

// ---------------------------------------------------------------------------
// Fused prep: edge-dtype detect + W->bf16^T + x->bf16 + zero counts/ovcnt.
// ---------------------------------------------------------------------------
__global__ __launch_bounds__(256) void convert_all_kernel(
        const float* __restrict__ W1, const float* __restrict__ W2,
        unsigned short* __restrict__ w1bf, unsigned short* __restrict__ w2bf,
        const float* __restrict__ x, unsigned short* __restrict__ xb, int total4,
        const int* __restrict__ ei, int* __restrict__ flag,
        int* __restrict__ counts, int* __restrict__ ovcnt, int M, int xbBlocks) {
    int b = blockIdx.x;
    if (b == 0 && threadIdx.x == 0) {
        int orsum = 0;
#pragma unroll
        for (int i = 0; i < 128; ++i) orsum |= ei[2 * i + 1];
        flag[0] = (orsum == 0) ? 1 : 0;
    }
    if (b < 128) {
        const float* W = (b < 64) ? W1 : W2;
        unsigned short* o = (b < 64) ? w1bf : w2bf;
        int idx = (b & 63) * 256 + threadIdx.x;   // idx = k*128+n
        int k = idx >> 7, n = idx & 127;
        o[n * 128 + k] = f2bf(W[idx]);
    } else if (b < 128 + xbBlocks) {
        int i = (b - 128) * 256 + threadIdx.x;
        if (i < total4) {
            float4 v = *(const float4*)&x[(size_t)i * 4];
            ushort4v o;
            o.x = f2bf(v.x); o.y = f2bf(v.y); o.z = f2bf(v.z); o.w = f2bf(v.w);
            *(ushort4v*)&xb[(size_t)i * 4] = o;
        }
    } else {
        int i = (b - 128 - xbBlocks) * 256 + threadIdx.x;  // int4 index
        int base = i * 4;
        if (base + 3 < M) {
            ((int4*)counts)[i] = make_int4(0, 0, 0, 0);
        } else {
            for (int j = base; j < M; ++j) counts[j] = 0;
        }
        if (i == 0) ovcnt[0] = 0;
    }
}

// ---------------------------------------------------------------------------
// Slab fill v3: dst-range sweeps for temporal write clustering.
// Grid = FILL_BLOCKS (all co-resident). Each thread loads its <=EPT edges
// into registers once, then loops NGRP sweeps; sweep s scatters only edges
// with dst in [s*sz, (s+1)*sz) -> active slab region 400 KB/XCD, L2-resident,
// each line dirtied+evicted ~once. slab layout [grp][node][SSLOT]: every
// 64B line belongs to one grp (~XCD). counts layout [grp][N].
// ---------------------------------------------------------------------------
__global__ __launch_bounds__(256) void fill_slab_kernel(
        const void* __restrict__ eiv, const int* __restrict__ flag,
        int* __restrict__ counts, int* __restrict__ ovcnt,
        int2* __restrict__ ov, int* __restrict__ slab, int E, int N, int nblk) {
    const int tid = blockIdx.x * 256 + threadIdx.x;
    const int stride = nblk * 256;
    const int grp = blockIdx.x & (NGRP - 1);
    const int is64 = flag[0];

    int sr[EPT], ds[EPT];
    int k = 0;
    for (int e = tid; e < E && k < EPT; e += stride) {
        sr[k] = load_idx(eiv, is64, (size_t)e);
        ds[k] = load_idx(eiv, is64, (size_t)E + e);
        ++k;
    }

    const int sz = (N + NGRP - 1) / NGRP;
    for (int s = 0; s < NGRP; ++s) {
        int lo = s * sz, hi = lo + sz;
#pragma unroll
        for (int i = 0; i < EPT; ++i) {
            if (i < k && ds[i] >= lo && ds[i] < hi) {
                int pos = atomicAdd(&counts[(size_t)grp * N + ds[i]], 1);
                if (pos < SSLOT)
                    slab[((size_t)grp * N + ds[i]) * SSLOT + pos] = sr[i];
                else {
                    int o = atomicAdd(ovcnt, 1);
                    if (o < OVCAP) ov[o] = make_int2(ds[i], sr[i]);
                }
            }
        }
    }
}

// ---------------------------------------------------------------------------
// Gather-aggregate v3 (R7-proven drain, new slab layout). 32-lane group per
// node; slab candidates -> LDS compaction (ballot/popc, wave-sync) -> 8
// independent row gathers per batch. h = (1+eps)*x[n] + sum x[s].
// ---------------------------------------------------------------------------
__global__ __launch_bounds__(256) void agg_slab_kernel(
        const unsigned short* __restrict__ xb,
        const int* __restrict__ counts,       // [NGRP][N]
        const int* __restrict__ slab,         // [NGRP][N][SSLOT]
        const int* __restrict__ ovcnt, const int2* __restrict__ ov,
        const float* __restrict__ epsp,
        unsigned short* __restrict__ hb,      // bf16 h out (may be null)
        float* __restrict__ hf,               // fp32 h out (used if hb null)
        int N) {
    __shared__ int comp[8][64];
    const int lane = threadIdx.x & 31;
    const int grpq = threadIdx.x >> 5;        // 0..7 node group in block
    const int base = threadIdx.x & 32;        // ballot shift for 32-lane group
    const int node = blockIdx.x * 8 + grpq;
    if (node >= N) return;
    const int c = lane * 4;
    const float epsv = 1.0f + epsp[0];

    // lane l covers seg g=l>>2, slots (l&3)*2, (l&3)*2+1
    int g = lane >> 2, s0 = (lane & 3) * 2;
    int2 sl = *(const int2*)&slab[((size_t)g * N + node) * SSLOT + s0];
    int cnt = min(counts[(size_t)g * N + node], SSLOT);
    bool v0 = s0 < cnt, v1 = (s0 + 1) < cnt;
    unsigned m0 = (unsigned)(__ballot(v0) >> base);
    unsigned m1 = (unsigned)(__ballot(v1) >> base);
    int t0 = __popc(m0);
    int total = t0 + __popc(m1);
    unsigned lt = (lane == 0) ? 0u : (~0u >> (32 - lane));
    if (v0) comp[grpq][__popc(m0 & lt)] = sl.x;
    if (v1) comp[grpq][t0 + __popc(m1 & lt)] = sl.y;
    // wave-synchronous LDS: same wave writes then reads its own slice

    ushort4v own = *(const ushort4v*)&xb[(size_t)node * DFEAT + c];
    float ax = epsv * bf2f(own.x), ay = epsv * bf2f(own.y);
    float az = epsv * bf2f(own.z), aw = epsv * bf2f(own.w);

    for (int i = 0; i < total; i += 8) {
        int4 qa = *(const int4*)&comp[grpq][i];
        int4 qb = *(const int4*)&comp[grpq][i + 4];
        int rem = total - i;
        int sj[8];
        sj[0] = qa.x;
        sj[1] = (rem > 1) ? qa.y : qa.x;
        sj[2] = (rem > 2) ? qa.z : qa.x;
        sj[3] = (rem > 3) ? qa.w : qa.x;
        sj[4] = (rem > 4) ? qb.x : qa.x;
        sj[5] = (rem > 5) ? qb.y : qa.x;
        sj[6] = (rem > 6) ? qb.z : qa.x;
        sj[7] = (rem > 7) ? qb.w : qa.x;
        ushort4v u[8];
#pragma unroll
        for (int j = 0; j < 8; ++j)
            u[j] = *(const ushort4v*)&xb[(size_t)sj[j] * DFEAT + c];
#pragma unroll
        for (int j = 0; j < 8; ++j) {
            if (rem > j) {
                ax += bf2f(u[j].x); ay += bf2f(u[j].y);
                az += bf2f(u[j].z); aw += bf2f(u[j].w);
            }
        }
    }

    // overflow replay (expected ~1K entries; broadcast reads, L2-cached)
    int ovn = min(ovcnt[0], OVCAP);
    int trips = (ovn + 31) >> 5;
    for (int t = 0; t < trips; ++t) {
        int j = t * 32 + lane;
        int2 e = (j < ovn) ? ov[j] : make_int2(-1, 0);
        unsigned long long b = __ballot(e.x == node);
        unsigned m = (unsigned)(b >> base);
        while (m) {
            int l = __ffs(m) - 1; m &= m - 1;
            int s = __shfl(e.y, base + l, 64);
            ushort4v u = *(const ushort4v*)&xb[(size_t)s * DFEAT + c];
            ax += bf2f(u.x); ay += bf2f(u.y);
            az += bf2f(u.z); aw += bf2f(u.w);
        }
    }

    if (hb) {
        ushort4v hv;
        hv.x = f2bf(ax); hv.y = f2bf(ay); hv.z = f2bf(az); hv.w = f2bf(aw);
        *(ushort4v*)&hb[(size_t)node * DFEAT + c] = hv;
    } else {
        *(float4*)&hf[(size_t)node * DFEAT + c] = make_float4(ax, ay, az, aw);
    }
}

// ---------------------------------------------------------------------------
// MFMA MLP (R4-proven): out = relu(h@W1+b1)@W2+b2, bf16 in / fp32 accum.
// ---------------------------------------------------------------------------
__global__ __launch_bounds__(256) void mlp_mfma_kernel(
        const unsigned short* __restrict__ hb,
        const float* __restrict__ hsrc,
        const unsigned short* __restrict__ w1bf,
        const unsigned short* __restrict__ w2bf,
        const float* __restrict__ b1, const float* __restrict__ b2,
        float* __restrict__ out, int N) {
    __shared__ unsigned short hlds[64 * 136];
    __shared__ unsigned short wlds[128 * 136];

    const int tid  = threadIdx.x;
    const int node0 = blockIdx.x * 64;
    const int lane = tid & 63;
    const int w    = tid >> 6;
    const int l15  = lane & 15;
    const int quad = lane >> 4;

    if (hb) {
        for (int i = tid; i < 64 * 16; i += 256) {
            int m = i >> 4, k0 = (i & 15) * 8;
            int node = node0 + m;
            short8v v = {0, 0, 0, 0, 0, 0, 0, 0};
            if (node < N) v = *(const short8v*)&hb[(size_t)node * DFEAT + k0];
            *(short8v*)&hlds[m * 136 + k0] = v;
        }
    } else {
        for (int i = tid; i < 64 * 32; i += 256) {
            int m = i >> 5, c = (i & 31) * 4;
            int node = node0 + m;
            float4 v = make_float4(0.f, 0.f, 0.f, 0.f);
            if (node < N) v = *(const float4*)&hsrc[(size_t)node * DFEAT + c];
            ushort4v o;
            o.x = f2bf(v.x); o.y = f2bf(v.y); o.z = f2bf(v.z); o.w = f2bf(v.w);
            *(ushort4v*)&hlds[m * 136 + c] = o;
        }
    }
    for (int i = tid; i < 128 * 16; i += 256) {
        int n = i >> 4, k0 = (i & 15) * 8;
        *(short8v*)&wlds[n * 136 + k0] = *(const short8v*)&w1bf[n * 128 + k0];
    }
    __syncthreads();

    const unsigned short* ha = &hlds[(w * 16 + l15) * 136 + quad * 8];

    for (int layer = 0; layer < 2; ++layer) {
        if (layer == 1) {
            __syncthreads();
            for (int i = tid; i < 128 * 16; i += 256) {
                int n = i >> 4, k0 = (i & 15) * 8;
                *(short8v*)&wlds[n * 136 + k0] = *(const short8v*)&w2bf[n * 128 + k0];
            }
            __syncthreads();
        }

        f32x4 acc[8];
#pragma unroll
        for (int nt = 0; nt < 8; ++nt) acc[nt] = (f32x4){0.f, 0.f, 0.f, 0.f};

#pragma unroll
        for (int s = 0; s < 4; ++s) {
            short8v a = *(const short8v*)&ha[s * 32];
#pragma unroll
            for (int nt = 0; nt < 8; ++nt) {
                short8v bf = *(const short8v*)&wlds[(nt * 16 + l15) * 136 + quad * 8 + s * 32];
                acc[nt] = __builtin_amdgcn_mfma_f32_16x16x32_bf16(a, bf, acc[nt], 0, 0, 0);
            }
        }

        const float* bias = layer ? b2 : b1;
        if (layer == 0) {
#pragma unroll
            for (int nt = 0; nt < 8; ++nt) {
                float bv = bias[nt * 16 + l15];
#pragma unroll
                for (int r = 0; r < 4; ++r) {
                    float v = fmaxf(acc[nt][r] + bv, 0.f);
                    hlds[(w * 16 + quad * 4 + r) * 136 + nt * 16 + l15] = f2bf(v);
                }
            }
        } else {
#pragma unroll
            for (int nt = 0; nt < 8; ++nt) {
                float bv = bias[nt * 16 + l15];
#pragma unroll
                for (int r = 0; r < 4; ++r) {
                    int node = node0 + w * 16 + quad * 4 + r;
                    if (node < N)
                        out[(size_t)node * DFEAT + nt * 16 + l15] = acc[nt][r] + bv;
                }
            }
        }
    }
}

// ===========================================================================
// Fallback (tiny ws): atomic scatter + fp32 vector MLP
// ===========================================================================
__global__ void detect_idx_kernel(const int* __restrict__ ei, int* __restrict__ flag) {
    if (threadIdx.x == 0 && blockIdx.x == 0) {
        int orsum = 0;
#pragma unroll
        for (int i = 0; i < 128; ++i) orsum |= ei[2 * i + 1];
        flag[0] = (orsum == 0) ? 1 : 0;
    }
}

__global__ __launch_bounds__(256) void scatter_kernel(
        const float* __restrict__ x, const void* __restrict__ eiv,
        const int* __restrict__ flag, float* __restrict__ agg, int E) {
    unsigned gid = blockIdx.x * 256u + threadIdx.x;
    unsigned e = gid >> 5;
    if (e >= (unsigned)E) return;
    int c = (gid & 31u) * 4;
    int is64 = flag[0];
    int src = load_idx(eiv, is64, (size_t)e);
    int dst = load_idx(eiv, is64, (size_t)E + e);
    float4 v = *(const float4*)&x[(size_t)src * DFEAT + c];
    float* p = &agg[(size_t)dst * DFEAT + c];
    unsafeAtomicAdd(p + 0, v.x);
    unsafeAtomicAdd(p + 1, v.y);
    unsafeAtomicAdd(p + 2, v.z);
    unsafeAtomicAdd(p + 3, v.w);
}

__global__ __launch_bounds__(256) void mlp_kernel(
        const float* __restrict__ xp,
        const float* __restrict__ W1, const float* __restrict__ b1,
        const float* __restrict__ W2, const float* __restrict__ b2,
        const float* __restrict__ epsp, float* __restrict__ out) {
    __shared__ float hs[32][DFEAT];
    __shared__ float Wc[64][DFEAT];

    const int tid = threadIdx.x;
    const int node0 = blockIdx.x * 32;
    const float epsv = 1.0f + epsp[0];

    for (int i = tid; i < 32 * (DFEAT / 4); i += 256) {
        int n = i >> 5;
        int c = (i & 31) * 4;
        size_t off = (size_t)(node0 + n) * DFEAT + c;
        float4 h = *(const float4*)&out[off];
        float4 xv = *(const float4*)&xp[off];
        h.x += epsv * xv.x; h.y += epsv * xv.y;
        h.z += epsv * xv.z; h.w += epsv * xv.w;
        *(float4*)&hs[n][c] = h;
    }

    const int og = (tid & 31) * 4;
    const int ng = (tid >> 5) * 4;

    for (int layer = 0; layer < 2; ++layer) {
        const float* W = layer ? W2 : W1;
        const float* b = layer ? b2 : b1;

        float acc[4][4];
#pragma unroll
        for (int j = 0; j < 4; ++j) {
            float bj = b[og + j];
#pragma unroll
            for (int i = 0; i < 4; ++i) acc[i][j] = bj;
        }

        for (int chunk = 0; chunk < 2; ++chunk) {
            __syncthreads();
            for (int i = tid; i < 64 * (DFEAT / 4); i += 256) {
                int r = i >> 5;
                int c = (i & 31) * 4;
                *(float4*)&Wc[r][c] =
                    *(const float4*)&W[(size_t)(chunk * 64 + r) * DFEAT + c];
            }
            __syncthreads();
            const int kb = chunk * 64;
            for (int k = 0; k < 64; k += 4) {
                float4 h4[4], w4[4];
#pragma unroll
                for (int i = 0; i < 4; ++i)
                    h4[i] = *(const float4*)&hs[ng + i][kb + k];
#pragma unroll
                for (int j = 0; j < 4; ++j)
                    w4[j] = *(const float4*)&Wc[k + j][og];
#pragma unroll
                for (int i = 0; i < 4; ++i) {
                    acc[i][0] += h4[i].x * w4[0].x + h4[i].y * w4[1].x
                               + h4[i].z * w4[2].x + h4[i].w * w4[3].x;
                    acc[i][1] += h4[i].x * w4[0].y + h4[i].y * w4[1].y
                               + h4[i].z * w4[2].y + h4[i].w * w4[3].y;
                    acc[i][2] += h4[i].x * w4[0].z + h4[i].y * w4[1].z
                               + h4[i].z * w4[2].z + h4[i].w * w4[3].z;
                    acc[i][3] += h4[i].x * w4[0].w + h4[i].y * w4[1].w
                               + h4[i].z * w4[2].w + h4[i].w * w4[3].w;
                }
            }
        }
        __syncthreads();

        if (layer == 0) {
#pragma unroll
            for (int i = 0; i < 4; ++i) {
                float4 r;
                r.x = fmaxf(acc[i][0], 0.0f);
                r.y = fmaxf(acc[i][1], 0.0f);
                r.z = fmaxf(acc[i][2], 0.0f);
                r.w = fmaxf(acc[i][3], 0.0f);
                *(float4*)&hs[ng + i][og] = r;
            }
        } else {
#pragma unroll
            for (int i = 0; i < 4; ++i) {
                float4 r;
                r.x = acc[i][0]; r.y = acc[i][1];
                r.z = acc[i][2]; r.w = acc[i][3];
                *(float4*)&out[(size_t)(node0 + ng + i) * DFEAT + og] = r;
            }
        }
    }
}

extern "C" void kernel_launch(void* const* d_in, const int* in_sizes, int n_in,
                              void* d_out, int out_size, void* d_ws, size_t ws_size,
                              hipStream_t stream) {
    const float* x   = (const float*)d_in[0];
    const void*  ei  = d_in[1];
    const float* W1  = (const float*)d_in[2];
    const float* b1  = (const float*)d_in[3];
    const float* W2  = (const float*)d_in[4];
    const float* b2  = (const float*)d_in[5];
    const float* eps = (const float*)d_in[6];
    float* out = (float*)d_out;

    const int N = in_sizes[0] / DFEAT;      // 100000
    const int E = in_sizes[1] / 2;          // 1600000
    const int M = NGRP * N;                 // 800000 segments
    const int total4 = N * (DFEAT / 4);     // 3.2M float4s in x

    // ---- T1 layout: [flag][wbf][xb][counts][ovcnt][ov][slab][hb?] ----
    char* p = (char*)d_ws;
    int* flag = (int*)p;                        p += 64;
    unsigned short* w1bf = (unsigned short*)p;  p += 128 * 128 * 2;
    unsigned short* w2bf = (unsigned short*)p;  p += 128 * 128 * 2;
    unsigned short* xb = (unsigned short*)p;    p += (size_t)N * DFEAT * 2;
    int* counts = (int*)p;                      p += (size_t)M * 4;
    int* ovcnt = (int*)p;                       p += 64;
    int2* ov = (int2*)p;                        p += (size_t)OVCAP * 8;
    int* slab = (int*)p;                        p += (size_t)M * SSLOT * 4;
    size_t need_slim = (size_t)(p - (char*)d_ws);
    unsigned short* hb = (unsigned short*)p;    p += (size_t)N * DFEAT * 2;
    size_t need_full = (size_t)(p - (char*)d_ws);

    if (ws_size >= need_slim) {
        bool full = (ws_size >= need_full);
        int xbBlocks = (total4 + 255) / 256;
        int czBlocks = (M / 4 + 255) / 256;
        convert_all_kernel<<<128 + xbBlocks + czBlocks, 256, 0, stream>>>(
            W1, W2, w1bf, w2bf, x, xb, total4, (const int*)ei, flag,
            counts, ovcnt, M, xbBlocks);
        int nblk = FILL_BLOCKS;
        if ((size_t)E > (size_t)FILL_BLOCKS * 256 * EPT)
            nblk = (E + 256 * EPT - 1) / (256 * EPT);
        fill_slab_kernel<<<nblk, 256, 0, stream>>>(
            ei, flag, counts, ovcnt, ov, slab, E, N, nblk);
        agg_slab_kernel<<<(N + 7) / 8, 256, 0, stream>>>(
            xb, counts, slab, ovcnt, ov, eps,
            full ? hb : nullptr, out, N);
        mlp_mfma_kernel<<<(N + 63) / 64, 256, 0, stream>>>(
            full ? hb : nullptr, out, w1bf, w2bf, b1, b2, out, N);
        return;
    }

    // ---- fallback: atomic scatter + fp32 MLP ----
    int* flag3 = (int*)d_ws;
    detect_idx_kernel<<<1, 64, 0, stream>>>((const int*)ei, flag3);
    hipMemsetAsync(d_out, 0, (size_t)out_size * sizeof(float), stream);
    unsigned total = (unsigned)E * 32u;
    scatter_kernel<<<(total + 255u) / 256u, 256, 0, stream>>>(x, ei, flag3, out, E);
    mlp_kernel<<<N / 32, 256, 0, stream>>>(x, W1, b1, W2, b2, eps, out);
}